// Round 11
// baseline (1006.320 us; speedup 1.0000x reference)
//
#include <hip/hip_runtime.h>
#include <hip/hip_bf16.h>

#define NN 65536
#define DM 1024
#define NH 16
#define KNB 4096
#define DEX 20
#define EPSV 1e-5f

typedef __attribute__((ext_vector_type(8))) short bf16x8;
typedef __attribute__((ext_vector_type(4))) float f32x4;

__device__ __forceinline__ unsigned short f2bf(float f){
  unsigned u = __builtin_bit_cast(unsigned, f);
  u += 0x7fffu + ((u >> 16) & 1u);
  return (unsigned short)(u >> 16);
}
__device__ __forceinline__ float bf2f(unsigned short s){
  return __builtin_bit_cast(float, ((unsigned)s) << 16);
}
__device__ __forceinline__ float wred(float v){
  #pragma unroll
  for (int s = 32; s; s >>= 1) v += __shfl_down(v, s);
  return v;
}

// opaque LDS read: compiler cannot see this is an LDS access -> inserts NO
// hazard waits; we own all waits (lgkmcnt(0)+sched_barrier per rule #18).
__device__ __forceinline__ bf16x8 ldsr128(const unsigned short* p){
  bf16x8 r;
  unsigned a = (unsigned)(size_t)(const __attribute__((address_space(3))) void*)p;
  asm volatile("ds_read_b128 %0, %1" : "=v"(r) : "v"(a));
  return r;
}

// ---------- scatter local_bias rows into extra (N x 20); extra pre-zeroed ----------
__global__ void k_scatter(const float* __restrict__ lb, const int* __restrict__ nidx,
                          float* __restrict__ extra){
  int i = blockIdx.x * 256 + threadIdx.x;
  if (i < KNB * DEX){
    int j = i / DEX, col = i - j * DEX;
    extra[(size_t)nidx[j] * DEX + col] = lb[i];
  }
}

// ---------- convert MLP weights to bf16: Wcomb (2048x1024) + W2b (1024x1024) ----------
__global__ void k_convw(const float* __restrict__ gateW, const float* __restrict__ fuseW1,
                        const float* __restrict__ fuseW2,
                        unsigned short* __restrict__ Wcomb, unsigned short* __restrict__ W2b){
  int i = blockIdx.x * 256 + threadIdx.x;
  if (i < 2048 * 1024){
    int o = i >> 10, d = i & 1023;
    float v = (o < 1024) ? gateW[(size_t)o * 2048 + d] : fuseW1[(size_t)(o - 1024) * 2048 + d];
    Wcomb[i] = f2bf(v);
  } else {
    int j = i - 2048 * 1024;
    W2b[j] = f2bf(fuseW2[j]);
  }
}

// ---------- LN of center row (norm_c) -> hcln[1024] ----------
__global__ void k_cln(const float* __restrict__ h, const int* __restrict__ cidx,
                      const float* __restrict__ cw, const float* __restrict__ cb,
                      float* __restrict__ hcln){
  int t = threadIdx.x, lane = t & 63, wid = t >> 6;
  int c = *cidx;
  const float4 x = *(const float4*)(h + (size_t)c * DM + t * 4);
  float s  = x.x + x.y + x.z + x.w;
  float ss = x.x * x.x + x.y * x.y + x.z * x.z + x.w * x.w;
  __shared__ float rs[4], rq[4];
  s = wred(s); ss = wred(ss);
  if (lane == 0){ rs[wid] = s; rq[wid] = ss; }
  __syncthreads();
  float mean = (rs[0] + rs[1] + rs[2] + rs[3]) * (1.0f / DM);
  float var  = (rq[0] + rq[1] + rq[2] + rq[3]) * (1.0f / DM) - mean * mean;
  float rstd = rsqrtf(var + EPSV);
  const float4 w = *(const float4*)(cw + t * 4);
  const float4 b = *(const float4*)(cb + t * 4);
  float4 o;
  o.x = (x.x - mean) * rstd * w.x + b.x;
  o.y = (x.y - mean) * rstd * w.y + b.y;
  o.z = (x.z - mean) * rstd * w.z + b.z;
  o.w = (x.w - mean) * rstd * w.w + b.w;
  *(float4*)(hcln + t * 4) = o;
}

// ---------- q[o] = hcln . Wq[o,:] ----------
__global__ void k_q(const float* __restrict__ hcln, const float* __restrict__ Wq,
                    float* __restrict__ q){
  int lane = threadIdx.x & 63, wid = threadIdx.x >> 6;
  float hv[16];
  #pragma unroll
  for (int j = 0; j < 16; j++) hv[j] = hcln[lane + 64 * j];
  #pragma unroll
  for (int oi = 0; oi < 4; oi++){
    int o = blockIdx.x * 16 + wid * 4 + oi;
    const float* wr = Wq + (size_t)o * DM;
    float a = 0.f;
    #pragma unroll
    for (int j = 0; j < 16; j++) a = fmaf(hv[j], wr[lane + 64 * j], a);
    a = wred(a);
    if (lane == 0) q[o] = a;
  }
}

// ---------- qkt[hh,i] = (sum_d q[hh*64+d] * Wk[hh*64+d, i]) / 8 ----------
__global__ void k_qkt(const float* __restrict__ q, const float* __restrict__ Wk,
                      float* __restrict__ qkt){
  int idx = blockIdx.x * 256 + threadIdx.x;   // 0..16383
  int hh = idx >> 10, i = idx & 1023;
  float a = 0.f;
  #pragma unroll 8
  for (int d = 0; d < 64; d++) a = fmaf(q[hh * 64 + d], Wk[(size_t)(hh * 64 + d) * DM + i], a);
  qkt[idx] = a * 0.125f;
}

// ---------- head constants: c12[h] = aw.qkt[h]; c12[16+h] = ab.qkt[h] ----------
__global__ void k_c12(const float* __restrict__ qkt, const float* __restrict__ aw,
                      const float* __restrict__ ab, float* __restrict__ c12){
  const int hh = blockIdx.x >> 1, which = blockIdx.x & 1, lane = threadIdx.x;
  const float* src = which ? ab : aw;
  float a = 0.f;
  #pragma unroll
  for (int j = 0; j < 16; j++) a = fmaf(src[lane + 64 * j], qkt[hh * DM + lane + 64 * j], a);
  a = wred(a);
  if (lane == 0) c12[which * NH + hh] = a;
}

// ---------- Qa[h][d] = bf16(qkt[h][d] * aw[d])  (B operand for logits MFMA) ----------
__global__ void k_qa(const float* __restrict__ qkt, const float* __restrict__ aw,
                     unsigned short* __restrict__ Qa){
  const int i = blockIdx.x * 256 + threadIdx.x;   // 16384
  Qa[i] = f2bf(qkt[i] * aw[i & (DM - 1)]);
}

// ---------- geometric bias per (n, head): biasT[n*16+h] ----------
__global__ void k_bias(const float* __restrict__ rbf, const float* __restrict__ seqsep,
                       const float* __restrict__ extra, const float* __restrict__ wbias,
                       float* __restrict__ biasT){
  const int i = blockIdx.x * 256 + threadIdx.x;   // < NN*NH
  const int n = i >> 4, hh = i & 15;
  const float* wb = wbias + hh * 40;
  float bb = 0.f;
  #pragma unroll
  for (int j = 0; j < 16; j++) bb = fmaf(rbf[(size_t)n * 16 + j], wb[j], bb);
  #pragma unroll
  for (int j = 0; j < 4; j++)  bb = fmaf(seqsep[(size_t)n * 4 + j], wb[16 + j], bb);
  #pragma unroll
  for (int j = 0; j < 20; j++) bb = fmaf(extra[(size_t)n * DEX + j], wb[20 + j], bb);
  biasT[i] = bb;
}

// ---------- lean LN pass: wave-per-row, no LDS, no sync, no spill ----------
__global__ void k_lnpass(const float* __restrict__ h, float* __restrict__ meanb,
                         float* __restrict__ rstdb, unsigned short* __restrict__ hbf){
  const int lane = threadIdx.x & 63, w = threadIdx.x >> 6;
  const int gw = blockIdx.x * 4 + w;
  #pragma unroll
  for (int rr = 0; rr < 2; rr++){
    const int n = gw * 2 + rr;
    const float* hp = h + (size_t)n * DM + lane * 16;
    const float4 x0 = *(const float4*)(hp);
    const float4 x1 = *(const float4*)(hp + 4);
    const float4 x2 = *(const float4*)(hp + 8);
    const float4 x3 = *(const float4*)(hp + 12);
    float s  = (x0.x + x0.y + x0.z + x0.w) + (x1.x + x1.y + x1.z + x1.w)
             + (x2.x + x2.y + x2.z + x2.w) + (x3.x + x3.y + x3.z + x3.w);
    float ss = x0.x*x0.x + x0.y*x0.y + x0.z*x0.z + x0.w*x0.w
             + x1.x*x1.x + x1.y*x1.y + x1.z*x1.z + x1.w*x1.w
             + x2.x*x2.x + x2.y*x2.y + x2.z*x2.z + x2.w*x2.w
             + x3.x*x3.x + x3.y*x3.y + x3.z*x3.z + x3.w*x3.w;
    #pragma unroll
    for (int m = 1; m < 64; m <<= 1){ s += __shfl_xor(s, m); ss += __shfl_xor(ss, m); }
    unsigned short* op = hbf + (size_t)n * DM + lane * 16;
    ushort4 o;
    o.x = f2bf(x0.x); o.y = f2bf(x0.y); o.z = f2bf(x0.z); o.w = f2bf(x0.w);
    *(ushort4*)(op) = o;
    o.x = f2bf(x1.x); o.y = f2bf(x1.y); o.z = f2bf(x1.z); o.w = f2bf(x1.w);
    *(ushort4*)(op + 4) = o;
    o.x = f2bf(x2.x); o.y = f2bf(x2.y); o.z = f2bf(x2.z); o.w = f2bf(x2.w);
    *(ushort4*)(op + 8) = o;
    o.x = f2bf(x3.x); o.y = f2bf(x3.y); o.z = f2bf(x3.z); o.w = f2bf(x3.w);
    *(ushort4*)(op + 12) = o;
    if (lane == 0){
      const float mean = s * (1.0f / DM);
      meanb[n] = mean;
      rstdb[n] = rsqrtf(ss * (1.0f / DM) - mean * mean + EPSV);
    }
  }
}

#define MFMA16(a, b, c) __builtin_amdgcn_mfma_f32_16x16x32_bf16(a, b, c, 0, 0, 0)

// ---------- logitsT[n][h] via MFMA: S1 = hbf @ Qa^T, epilogue folds rstd/mean/c12/bias ----------
__launch_bounds__(256)
__global__ void k_logits(const unsigned short* __restrict__ hbf, const unsigned short* __restrict__ Qa,
                         const float* __restrict__ meanb, const float* __restrict__ rstdb,
                         const float* __restrict__ c12, const float* __restrict__ biasT,
                         float* __restrict__ logitsT){
  const int lane = threadIdx.x & 63, w = threadIdx.x >> 6;
  const int n0 = (blockIdx.x * 4 + w) * 16;
  const int fr = lane & 15, kq = lane >> 4;
  f32x4 acc = {0.f, 0.f, 0.f, 0.f};
  const unsigned short* ap = hbf + (size_t)(n0 + fr) * DM + kq * 8;
  const unsigned short* bp = Qa + fr * DM + kq * 8;
  #pragma unroll 4
  for (int kt = 0; kt < DM; kt += 64){
    const bf16x8 a0 = *(const bf16x8*)(ap + kt);
    const bf16x8 b0 = *(const bf16x8*)(bp + kt);
    const bf16x8 a1 = *(const bf16x8*)(ap + kt + 32);
    const bf16x8 b1 = *(const bf16x8*)(bp + kt + 32);
    acc = MFMA16(a0, b0, acc);
    acc = MFMA16(a1, b1, acc);
  }
  const float C1 = c12[fr], C2 = c12[NH + fr];
  #pragma unroll
  for (int r = 0; r < 4; r++){
    const int n = n0 + kq * 4 + r;
    const float mean = meanb[n], rstd = rstdb[n];
    logitsT[(size_t)n * NH + fr] = rstd * acc[r] - rstd * mean * C1 + C2
                                   + biasT[(size_t)n * NH + fr];
  }
}

// ---------- softmax partials over [n][16] layout: 256 blocks ----------
__global__ void k_smpart(const float* __restrict__ logitsT, float* __restrict__ msp){
  const int t = threadIdx.x, lane = t & 63, w = t >> 6;
  const int hh = lane & 15, no = lane >> 4;
  const float* base = logitsT + ((size_t)blockIdx.x * 256 + w * 64) * NH;
  float m = -3.0e38f;
  #pragma unroll
  for (int it = 0; it < 16; it++)
    m = fmaxf(m, base[(it * 4 + no) * NH + hh]);
  m = fmaxf(m, __shfl_xor(m, 16));
  m = fmaxf(m, __shfl_xor(m, 32));
  float s = 0.f;
  #pragma unroll
  for (int it = 0; it < 16; it++)
    s += __expf(base[(it * 4 + no) * NH + hh] - m);
  s += __shfl_xor(s, 16);
  s += __shfl_xor(s, 32);
  __shared__ float sm[4][16], ssm[4][16];
  if (lane < 16){ sm[w][hh] = m; ssm[w][hh] = s; }
  __syncthreads();
  if (t < NH){
    const float M = fmaxf(fmaxf(sm[0][t], sm[1][t]), fmaxf(sm[2][t], sm[3][t]));
    const float S = ssm[0][t] * __expf(sm[0][t] - M) + ssm[1][t] * __expf(sm[1][t] - M)
                  + ssm[2][t] * __expf(sm[2][t] - M) + ssm[3][t] * __expf(sm[3][t] - M);
    msp[((size_t)blockIdx.x * NH + t) * 2]     = M;
    msp[((size_t)blockIdx.x * NH + t) * 2 + 1] = S;
  }
}

__global__ void k_smcomb(const float* __restrict__ msp, float* __restrict__ ms){
  const int lane = threadIdx.x;           // 64
  const int hh = lane & 15, g = lane >> 4;
  float M = -3.0e38f;
  for (int i = g; i < 256; i += 4) M = fmaxf(M, msp[((size_t)i * NH + hh) * 2]);
  M = fmaxf(M, __shfl_xor(M, 16));
  M = fmaxf(M, __shfl_xor(M, 32));
  float S = 0.f;
  for (int i = g; i < 256; i += 4)
    S += msp[((size_t)i * NH + hh) * 2 + 1] * __expf(msp[((size_t)i * NH + hh) * 2] - M);
  S += __shfl_xor(S, 16);
  S += __shfl_xor(S, 32);
  if (lane < NH){ ms[hh] = M; ms[16 + hh] = S; }
}

// ---------- softmax weights: wexp[n][h] = exp(logitsT - m[h]) ----------
__global__ void k_expw(const float* __restrict__ logitsT, const float* __restrict__ ms,
                       float* __restrict__ wexp){
  const int i = blockIdx.x * 256 + threadIdx.x;   // NN*NH/4 float4s
  const float4 v = ((const float4*)logitsT)[i];
  const int hb = (i & 3) * 4;
  float4 o;
  o.x = __expf(v.x - ms[hb]);
  o.y = __expf(v.y - ms[hb + 1]);
  o.z = __expf(v.z - ms[hb + 2]);
  o.w = __expf(v.w - ms[hb + 3]);
  ((float4*)wexp)[i] = o;
}

// ---------- u partials: upart[b,hh,d] = sum_rows wexp * LN(h) ----------
#define UB 256
__global__ void k_upart(const unsigned short* __restrict__ hbf, const float* __restrict__ meanb,
                        const float* __restrict__ rstdb, const float* __restrict__ aw,
                        const float* __restrict__ ab, const float* __restrict__ wexp,
                        float* __restrict__ upart){
  const int t = threadIdx.x, bb = blockIdx.x;
  const float4 w  = *(const float4*)(aw + t * 4);
  const float4 bv = *(const float4*)(ab + t * 4);
  float acc[NH][4];
  #pragma unroll
  for (int hh = 0; hh < NH; hh++){ acc[hh][0] = 0.f; acc[hh][1] = 0.f; acc[hh][2] = 0.f; acc[hh][3] = 0.f; }
  #pragma unroll 2
  for (int r = 0; r < NN / UB; r++){
    const int n = bb * (NN / UB) + r;
    const float mean = meanb[n], rstd = rstdb[n];
    const ushort4 hb = *(const ushort4*)(hbf + (size_t)n * DM + t * 4);
    const float l0 = (bf2f(hb.x) - mean) * rstd * w.x + bv.x;
    const float l1 = (bf2f(hb.y) - mean) * rstd * w.y + bv.y;
    const float l2 = (bf2f(hb.z) - mean) * rstd * w.z + bv.z;
    const float l3 = (bf2f(hb.w) - mean) * rstd * w.w + bv.w;
    const float4 e0 = *(const float4*)(wexp + (size_t)n * NH);
    const float4 e1 = *(const float4*)(wexp + (size_t)n * NH + 4);
    const float4 e2 = *(const float4*)(wexp + (size_t)n * NH + 8);
    const float4 e3 = *(const float4*)(wexp + (size_t)n * NH + 12);
#define ACC1(h, e) { acc[h][0] = fmaf(e, l0, acc[h][0]); acc[h][1] = fmaf(e, l1, acc[h][1]); \
                     acc[h][2] = fmaf(e, l2, acc[h][2]); acc[h][3] = fmaf(e, l3, acc[h][3]); }
    ACC1(0, e0.x)  ACC1(1, e0.y)  ACC1(2, e0.z)  ACC1(3, e0.w)
    ACC1(4, e1.x)  ACC1(5, e1.y)  ACC1(6, e1.z)  ACC1(7, e1.w)
    ACC1(8, e2.x)  ACC1(9, e2.y)  ACC1(10, e2.z) ACC1(11, e2.w)
    ACC1(12, e3.x) ACC1(13, e3.y) ACC1(14, e3.z) ACC1(15, e3.w)
#undef ACC1
  }
  #pragma unroll
  for (int hh = 0; hh < NH; hh++){
    float4 o; o.x = acc[hh][0]; o.y = acc[hh][1]; o.z = acc[hh][2]; o.w = acc[hh][3];
    *(float4*)(upart + ((size_t)bb * NH + hh) * DM + t * 4) = o;
  }
}

// ---------- two-level reduce of upart ----------
__global__ void k_ured1(const float* __restrict__ upart, float* __restrict__ up2){
  const int idx = (blockIdx.x & 63) * 256 + threadIdx.x;   // 0..16383
  const int sl  = blockIdx.x >> 6;                          // 0..15
  float s = 0.f;
  for (int b = sl * 16; b < sl * 16 + 16; b++) s += upart[(size_t)b * (NH * DM) + idx];
  up2[(size_t)sl * (NH * DM) + idx] = s;
}

__global__ void k_ured2(const float* __restrict__ up2, const float* __restrict__ ms,
                        float* __restrict__ u){
  const int idx = blockIdx.x * 256 + threadIdx.x;   // 0..16383
  const int hh = idx >> 10;
  float s = 0.f;
  #pragma unroll
  for (int sl = 0; sl < 16; sl++) s += up2[(size_t)sl * (NH * DM) + idx];
  u[idx] = s / ms[16 + hh];
}

// ---------- out_center[o] = u[head(o),:] . Wv[o,:] ----------
__global__ void k_oc(const float* __restrict__ u, const float* __restrict__ Wv,
                     float* __restrict__ oc){
  int lane = threadIdx.x & 63, wid = threadIdx.x >> 6;
  #pragma unroll
  for (int oi = 0; oi < 4; oi++){
    int o = blockIdx.x * 16 + wid * 4 + oi;
    const float* ur = u + (size_t)(o >> 6) * DM;
    const float* wr = Wv + (size_t)o * DM;
    float a = 0.f;
    #pragma unroll
    for (int j = 0; j < 16; j++) a = fmaf(ur[lane + 64 * j], wr[lane + 64 * j], a);
    a = wred(a);
    if (lane == 0) oc[o] = a;
  }
}

// ---------- hcnew[o] = h[c,o] + 0.5 * oc . Wo[o,:] ----------
__global__ void k_delta(const float* __restrict__ oc, const float* __restrict__ Wo,
                        const float* __restrict__ h, const int* __restrict__ cidx,
                        float* __restrict__ hcnew){
  int lane = threadIdx.x & 63, wid = threadIdx.x >> 6;
  int c = *cidx;
  float ov[16];
  #pragma unroll
  for (int j = 0; j < 16; j++) ov[j] = oc[lane + 64 * j];
  #pragma unroll
  for (int oi = 0; oi < 4; oi++){
    int o = blockIdx.x * 16 + wid * 4 + oi;
    const float* wr = Wo + (size_t)o * DM;
    float a = 0.f;
    #pragma unroll
    for (int j = 0; j < 16; j++) a = fmaf(ov[j], wr[lane + 64 * j], a);
    a = wred(a);
    if (lane == 0) hcnew[o] = h[(size_t)c * DM + o] + 0.5f * a;
  }
}

// ---------- rank-1 column biases: gbtot/fbtot ----------
__global__ void k_gbfb(const float* __restrict__ hcnew, const float* __restrict__ gateW,
                       const float* __restrict__ gateB, const float* __restrict__ fuseW1,
                       const float* __restrict__ fuseB1, float* __restrict__ gbtot,
                       float* __restrict__ fbtot){
  int lane = threadIdx.x & 63, wid = threadIdx.x >> 6;
  float hv[16];
  #pragma unroll
  for (int j = 0; j < 16; j++) hv[j] = hcnew[lane + 64 * j];
  #pragma unroll
  for (int oi = 0; oi < 4; oi++){
    int o = blockIdx.x * 16 + wid * 4 + oi;
    const float* gr = gateW + (size_t)o * 2048 + 1024;
    const float* fr = fuseW1 + (size_t)o * 2048 + 1024;
    float ga = 0.f, fa = 0.f;
    #pragma unroll
    for (int j = 0; j < 16; j++){
      ga = fmaf(hv[j], gr[lane + 64 * j], ga);
      fa = fmaf(hv[j], fr[lane + 64 * j], fa);
    }
    ga = wred(ga); fa = wred(fa);
    if (lane == 0){ gbtot[o] = ga + gateB[o]; fbtot[o] = fa + fuseB1[o]; }
  }
}

// ---------- MFMA GEMM, 128x128 tile, BK=64, 4 waves, 64KB LDS -> 2 blocks/CU ----------
// Same verified 8-phase skeleton collapsed to 4 phases/iter (2 K-tiles), 16 MFMA +
// 2 half-tile stages (4 loads) per phase, counted vmcnt(4) at P2/P4, raw s_barrier,
// opaque asm ds_read, 2-way-free swizzle (chunk ^= row&7 via lane identity).
// Ledger (iter i, k0=2i): P1: A(k0+1)->b1 | compute b0 frags 0,1
//                         P2: B(k0+2)->b0 | compute b0 frags 2,3 [vmcnt4]
//                         P3: A(k0+2)->b0 | compute b1 frags 0,1
//                         P4: B(k0+3)->b1 | compute b1 frags 2,3 [vmcnt4]
// Overwrite safety: each staged region's last ds_read is >=1 barrier earlier.
// vmcnt(4): only the current phase's 4 loads may remain in flight; everything
// read next phase has landed. Prologue: A0,B0->b0, B1->b1, vmcnt(4).
#define H64 ((size_t)64 * DM)
#define GLL16(gp, lp) __builtin_amdgcn_global_load_lds((const __attribute__((address_space(1))) void*)(gp), (__attribute__((address_space(3))) void*)(lp), 16, 0, 0)
#define SBAR() do { __builtin_amdgcn_sched_barrier(0); \
                    asm volatile("s_barrier" ::: "memory"); \
                    __builtin_amdgcn_sched_barrier(0); } while (0)

#define PHASE(BUF, QP, STG1, STL1, STG2, STL2, STK, DOVM) do {                         \
    if ((QP) == 0){                                                                   \
      _Pragma("unroll")                                                               \
      for (int nj = 0; nj < 4; nj++){                                                 \
        bq[nj][0] = ldsr128(lB + (BUF)*8192 + bBase + nj*1024 + kOff0);               \
        bq[nj][1] = ldsr128(lB + (BUF)*8192 + bBase + nj*1024 + kOff1);               \
      }                                                                               \
    }                                                                                 \
    bf16x8 a00 = ldsr128(lA + (BUF)*8192 + aBase + (2*(QP))*1024   + kOff0);          \
    bf16x8 a01 = ldsr128(lA + (BUF)*8192 + aBase + (2*(QP))*1024   + kOff1);          \
    bf16x8 a10 = ldsr128(lA + (BUF)*8192 + aBase + (2*(QP)+1)*1024 + kOff0);          \
    bf16x8 a11 = ldsr128(lA + (BUF)*8192 + aBase + (2*(QP)+1)*1024 + kOff1);          \
    stage(STG1, STL1, STK);                                                           \
    stage(STG2, STL2, STK);                                                           \
    SBAR();                                                                           \
    asm volatile("s_waitcnt lgkmcnt(0)" ::: "memory");                                \
    __builtin_amdgcn_sched_barrier(0);                                                \
    __builtin_amdgcn_s_setprio(1);                                                    \
    _Pragma("unroll")                                                                 \
    for (int nj = 0; nj < 4; nj++){                                                   \
      acc[2*(QP)][nj]   = MFMA16(a00, bq[nj][0], acc[2*(QP)][nj]);                    \
      acc[2*(QP)][nj]   = MFMA16(a01, bq[nj][1], acc[2*(QP)][nj]);                    \
      acc[2*(QP)+1][nj] = MFMA16(a10, bq[nj][0], acc[2*(QP)+1][nj]);                  \
      acc[2*(QP)+1][nj] = MFMA16(a11, bq[nj][1], acc[2*(QP)+1][nj]);                  \
    }                                                                                 \
    __builtin_amdgcn_s_setprio(0);                                                    \
    if (DOVM){ asm volatile("s_waitcnt vmcnt(4)" ::: "memory"); }                     \
    SBAR();                                                                           \
  } while (0)

template<int MODE>
__launch_bounds__(256, 2)
__global__ void k_gemm(const unsigned short* __restrict__ A, const unsigned short* __restrict__ B,
                       const float* __restrict__ bias0, const float* __restrict__ bias1,
                       const unsigned short* __restrict__ hsrcb, const unsigned short* __restrict__ gate,
                       unsigned short* __restrict__ og, unsigned short* __restrict__ ot,
                       float* __restrict__ of){
  __shared__ __attribute__((aligned(16))) unsigned short lA[16384];
  __shared__ __attribute__((aligned(16))) unsigned short lB[16384];
  const int NWG = (MODE == 0) ? 8192 : 4096;
  const int NYT = (MODE == 0) ? 16 : 8;
  const int bid = blockIdx.x;
  const int remap = (bid & 7) * (NWG >> 3) + (bid >> 3);
  const int m0 = (remap / NYT) * 128, n0 = (remap % NYT) * 128;

  const int tid = threadIdx.x, lane = tid & 63, w = tid >> 6;
  const int wm = w >> 1, wn = w & 1;

  f32x4 acc[4][4];
  #pragma unroll
  for (int i = 0; i < 4; i++){
    #pragma unroll
    for (int j = 0; j < 4; j++){ acc[i][j][0] = 0.f; acc[i][j][1] = 0.f; acc[i][j][2] = 0.f; acc[i][j][3] = 0.f; }
  }

  // staging: wave w covers rows {w*16+ln3, +8} of each 64-row half-tile
  const int ln3 = lane >> 3;
  const size_t stRow0 = (size_t)(w * 16 + ln3);
  const int sxor = ((lane & 7) ^ ln3) * 8;
  const size_t srcOff0 = stRow0 * DM + sxor;
  const size_t srcOff1 = (stRow0 + 8) * DM + sxor;
  const int dst0 = w * 1024 + lane * 8;
  const int dst1 = dst0 + 512;

  const unsigned short* gA = A + (size_t)m0 * DM;
  const unsigned short* gB = B + (size_t)n0 * DM;

  auto stage = [&](const unsigned short* g, unsigned short* ldsr, int kt){
    GLL16(g + srcOff0 + kt * 64, ldsr + dst0);
    GLL16(g + srcOff1 + kt * 64, ldsr + dst1);
  };

  const int fr = lane & 15;
  const int kq = lane >> 4;
  const int kOff0 = ((kq)     ^ (lane & 7)) * 8;
  const int kOff1 = ((4 + kq) ^ (lane & 7)) * 8;
  const int aBase = wm * 4096 + fr * 64;
  const int bBase = wn * 4096 + fr * 64;

  bf16x8 bq[4][2];

  // prologue: b0 <- A(0),B(0); b1 <- B(1). vmcnt(4): B(1)'s last 4 may fly.
  stage(gA,       lA,        0);
  stage(gA + H64, lA + 4096, 0);
  stage(gB,       lB,        0);
  stage(gB + H64, lB + 4096, 0);
  stage(gB,       lB + 8192, 1);
  stage(gB + H64, lB + 8192 + 4096, 1);
  asm volatile("s_waitcnt vmcnt(4)" ::: "memory");
  SBAR();

  #pragma unroll 1
  for (int i = 0; i < 8; i++){
    const int k0 = 2 * i;
    PHASE(0, 0, gA,       lA + 8192, gA + H64, lA + 8192 + 4096, k0 + 1,        false);
    PHASE(0, 1, gB,       lB,        gB + H64, lB + 4096,        (k0 + 2) & 15, true);
    PHASE(1, 0, gA,       lA,        gA + H64, lA + 4096,        (k0 + 2) & 15, false);
    PHASE(1, 1, gB,       lB + 8192, gB + H64, lB + 8192 + 4096, (k0 + 3) & 15, true);
  }

  const int r0 = kq * 4;
  #pragma unroll
  for (int mi = 0; mi < 4; mi++){
    #pragma unroll
    for (int nj = 0; nj < 4; nj++){
      const int gmb = m0 + wm * 64 + mi * 16 + r0;
      const int gn  = n0 + wn * 64 + nj * 16 + fr;
      #pragma unroll
      for (int r = 0; r < 4; r++){
        const int gm = gmb + r;
        const float x = acc[mi][nj][r];
        if (MODE == 0){
          if (gn < 1024){
            const float v = x + bias0[gn];
            og[(size_t)gm * DM + gn] = f2bf(1.0f / (1.0f + __expf(-v)));
          } else {
            const float v = x + bias1[gn - 1024];
            ot[(size_t)gm * DM + (gn - 1024)] = f2bf(v / (1.0f + __expf(-v)));
          }
        } else {
          const float v = x + bias0[gn];
          const float g = bf2f(gate[(size_t)gm * DM + gn]);
          of[(size_t)gm * DM + gn] = bf2f(hsrcb[(size_t)gm * DM + gn]) + 0.5f * g * v;
        }
      }
    }
  }
}

// ---------- overwrite center row ----------
__global__ void k_fixc(const float* __restrict__ hcnew, const int* __restrict__ cidx,
                       float* __restrict__ out){
  int t = threadIdx.x;
  int c = *cidx;
  out[(size_t)c * DM + t] = hcnew[t];
}

extern "C" void kernel_launch(void* const* d_in, const int* in_sizes, int n_in,
                              void* d_out, int out_size, void* d_ws, size_t ws_size,
                              hipStream_t stream){
  const float* h      = (const float*)d_in[0];
  const float* rbf    = (const float*)d_in[1];
  const float* seqsep = (const float*)d_in[2];
  const float* localb = (const float*)d_in[3];
  const float* ncw    = (const float*)d_in[4];
  const float* ncb    = (const float*)d_in[5];
  const float* naw    = (const float*)d_in[6];
  const float* nab    = (const float*)d_in[7];
  const float* Wq     = (const float*)d_in[8];
  const float* Wk     = (const float*)d_in[9];
  const float* Wv     = (const float*)d_in[10];
  const float* Wo     = (const float*)d_in[11];
  const float* Wbias  = (const float*)d_in[12];
  const float* gateW  = (const float*)d_in[13];
  const float* gateB  = (const float*)d_in[14];
  const float* fuseW1 = (const float*)d_in[15];
  const float* fuseB1 = (const float*)d_in[16];
  const float* fuseW2 = (const float*)d_in[17];
  const float* fuseB2 = (const float*)d_in[18];
  const int*   nbr    = (const int*)d_in[19];
  const int*   cidx   = (const int*)d_in[20];
  float* out = (float*)d_out;

  char* p = (char*)d_ws;
  auto alloc = [&](size_t nb){ char* r = p; p += (nb + 255) & ~(size_t)255; return r; };
  float* extra   = (float*)alloc((size_t)NN * DEX * 4);
  float* logitsT = (float*)alloc((size_t)NN * NH * 4);
  float* wexp    = (float*)alloc((size_t)NN * NH * 4);
  float* biasT   = (float*)alloc((size_t)NN * NH * 4);
  float* meanb   = (float*)alloc((size_t)NN * 4);
  float* rstdb   = (float*)alloc((size_t)NN * 4);
  float* ms      = (float*)alloc(32 * 4);
  float* msp     = (float*)alloc((size_t)256 * NH * 2 * 4);
  float* qkt     = (float*)alloc(NH * DM * 4);
  float* u       = (float*)alloc(NH * DM * 4);
  float* hcln    = (float*)alloc(DM * 4);
  float* qv      = (float*)alloc(DM * 4);
  float* oc      = (float*)alloc(DM * 4);
  float* hcnew   = (float*)alloc(DM * 4);
  float* gbtot   = (float*)alloc(DM * 4);
  float* fbtot   = (float*)alloc(DM * 4);
  float* c12     = (float*)alloc(32 * 4);
  float* up2     = (float*)alloc((size_t)16 * NH * DM * 4);
  float* upart   = (float*)alloc((size_t)UB * NH * DM * 4);
  unsigned short* Wcomb = (unsigned short*)alloc((size_t)2048 * 1024 * 2);
  unsigned short* W2b   = (unsigned short*)alloc((size_t)1024 * 1024 * 2);
  unsigned short* Qa    = (unsigned short*)alloc((size_t)NH * DM * 2);
  unsigned short* hbf   = (unsigned short*)alloc((size_t)NN * DM * 2);
  unsigned short* gateb = (unsigned short*)alloc((size_t)NN * DM * 2);
  unsigned short* t1    = (unsigned short*)alloc((size_t)NN * DM * 2);
  if ((size_t)(p - (char*)d_ws) > ws_size) return;  // clean fail instead of corruption

  hipMemsetAsync(extra, 0, (size_t)NN * DEX * 4, stream);
  k_scatter<<<(KNB * DEX + 255) / 256, 256, 0, stream>>>(localb, nbr, extra);
  k_convw<<<(3 * 1024 * 1024) / 256, 256, 0, stream>>>(gateW, fuseW1, fuseW2, Wcomb, W2b);
  k_cln<<<1, 256, 0, stream>>>(h, cidx, ncw, ncb, hcln);
  k_q<<<64, 256, 0, stream>>>(hcln, Wq, qv);
  k_qkt<<<64, 256, 0, stream>>>(qv, Wk, qkt);
  k_c12<<<32, 64, 0, stream>>>(qkt, naw, nab, c12);
  k_qa<<<64, 256, 0, stream>>>(qkt, naw, Qa);
  k_bias<<<NN * NH / 256, 256, 0, stream>>>(rbf, seqsep, extra, Wbias, biasT);
  k_lnpass<<<NN / 8, 256, 0, stream>>>(h, meanb, rstdb, hbf);
  k_logits<<<1024, 256, 0, stream>>>(hbf, Qa, meanb, rstdb, c12, biasT, logitsT);
  k_smpart<<<256, 256, 0, stream>>>(logitsT, msp);
  k_smcomb<<<1, 64, 0, stream>>>(msp, ms);
  k_expw<<<NN * NH / 4 / 256, 256, 0, stream>>>(logitsT, ms, wexp);
  k_upart<<<UB, 256, 0, stream>>>(hbf, meanb, rstdb, naw, nab, wexp, upart);
  k_ured1<<<1024, 256, 0, stream>>>(upart, up2);
  k_ured2<<<64, 256, 0, stream>>>(up2, ms, u);
  k_oc<<<64, 256, 0, stream>>>(u, Wv, oc);
  k_delta<<<64, 256, 0, stream>>>(oc, Wo, h, cidx, hcnew);
  k_gbfb<<<64, 256, 0, stream>>>(hcnew, gateW, gateB, fuseW1, fuseB1, gbtot, fbtot);
  k_gemm<0><<<8192, 256, 0, stream>>>(hbf, Wcomb, gbtot, fbtot, nullptr, nullptr, gateb, t1, nullptr);
  k_gemm<1><<<4096, 256, 0, stream>>>(t1, W2b, fuseB2, nullptr, hbf, gateb, nullptr, nullptr, out);
  k_fixc<<<1, 1024, 0, stream>>>(hcnew, cidx, out);
}

// Round 12
// 956.549 us; speedup vs baseline: 1.0520x; 1.0520x over previous
//
#include <hip/hip_runtime.h>
#include <hip/hip_bf16.h>

#define NN 65536
#define DM 1024
#define NH 16
#define KNB 4096
#define DEX 20
#define EPSV 1e-5f

typedef __attribute__((ext_vector_type(8))) short bf16x8;
typedef __attribute__((ext_vector_type(4))) float f32x4;

__device__ __forceinline__ unsigned short f2bf(float f){
  unsigned u = __builtin_bit_cast(unsigned, f);
  u += 0x7fffu + ((u >> 16) & 1u);
  return (unsigned short)(u >> 16);
}
__device__ __forceinline__ float bf2f(unsigned short s){
  return __builtin_bit_cast(float, ((unsigned)s) << 16);
}
__device__ __forceinline__ float wred(float v){
  #pragma unroll
  for (int s = 32; s; s >>= 1) v += __shfl_down(v, s);
  return v;
}

// opaque LDS read: compiler cannot see this is an LDS access -> inserts NO
// hazard waits; we own all waits (lgkmcnt(0)+sched_barrier per rule #18).
__device__ __forceinline__ bf16x8 ldsr128(const unsigned short* p){
  bf16x8 r;
  unsigned a = (unsigned)(size_t)(const __attribute__((address_space(3))) void*)p;
  asm volatile("ds_read_b128 %0, %1" : "=v"(r) : "v"(a));
  return r;
}

// ---------- scatter local_bias rows into extra (N x 20); extra pre-zeroed ----------
__global__ void k_scatter(const float* __restrict__ lb, const int* __restrict__ nidx,
                          float* __restrict__ extra){
  int i = blockIdx.x * 256 + threadIdx.x;
  if (i < KNB * DEX){
    int j = i / DEX, col = i - j * DEX;
    extra[(size_t)nidx[j] * DEX + col] = lb[i];
  }
}

// ---------- convert MLP weights to bf16: Wcomb (2048x1024) + W2b (1024x1024) ----------
__global__ void k_convw(const float* __restrict__ gateW, const float* __restrict__ fuseW1,
                        const float* __restrict__ fuseW2,
                        unsigned short* __restrict__ Wcomb, unsigned short* __restrict__ W2b){
  int i = blockIdx.x * 256 + threadIdx.x;
  if (i < 2048 * 1024){
    int o = i >> 10, d = i & 1023;
    float v = (o < 1024) ? gateW[(size_t)o * 2048 + d] : fuseW1[(size_t)(o - 1024) * 2048 + d];
    Wcomb[i] = f2bf(v);
  } else {
    int j = i - 2048 * 1024;
    W2b[j] = f2bf(fuseW2[j]);
  }
}

// ---------- LN of center row (norm_c) -> hcln[1024] ----------
__global__ void k_cln(const float* __restrict__ h, const int* __restrict__ cidx,
                      const float* __restrict__ cw, const float* __restrict__ cb,
                      float* __restrict__ hcln){
  int t = threadIdx.x, lane = t & 63, wid = t >> 6;
  int c = *cidx;
  const float4 x = *(const float4*)(h + (size_t)c * DM + t * 4);
  float s  = x.x + x.y + x.z + x.w;
  float ss = x.x * x.x + x.y * x.y + x.z * x.z + x.w * x.w;
  __shared__ float rs[4], rq[4];
  s = wred(s); ss = wred(ss);
  if (lane == 0){ rs[wid] = s; rq[wid] = ss; }
  __syncthreads();
  float mean = (rs[0] + rs[1] + rs[2] + rs[3]) * (1.0f / DM);
  float var  = (rq[0] + rq[1] + rq[2] + rq[3]) * (1.0f / DM) - mean * mean;
  float rstd = rsqrtf(var + EPSV);
  const float4 w = *(const float4*)(cw + t * 4);
  const float4 b = *(const float4*)(cb + t * 4);
  float4 o;
  o.x = (x.x - mean) * rstd * w.x + b.x;
  o.y = (x.y - mean) * rstd * w.y + b.y;
  o.z = (x.z - mean) * rstd * w.z + b.z;
  o.w = (x.w - mean) * rstd * w.w + b.w;
  *(float4*)(hcln + t * 4) = o;
}

// ---------- q[o] = hcln . Wq[o,:] ----------
__global__ void k_q(const float* __restrict__ hcln, const float* __restrict__ Wq,
                    float* __restrict__ q){
  int lane = threadIdx.x & 63, wid = threadIdx.x >> 6;
  float hv[16];
  #pragma unroll
  for (int j = 0; j < 16; j++) hv[j] = hcln[lane + 64 * j];
  #pragma unroll
  for (int oi = 0; oi < 4; oi++){
    int o = blockIdx.x * 16 + wid * 4 + oi;
    const float* wr = Wq + (size_t)o * DM;
    float a = 0.f;
    #pragma unroll
    for (int j = 0; j < 16; j++) a = fmaf(hv[j], wr[lane + 64 * j], a);
    a = wred(a);
    if (lane == 0) q[o] = a;
  }
}

// ---------- qkt[hh,i] = (sum_d q[hh*64+d] * Wk[hh*64+d, i]) / 8 ----------
__global__ void k_qkt(const float* __restrict__ q, const float* __restrict__ Wk,
                      float* __restrict__ qkt){
  int idx = blockIdx.x * 256 + threadIdx.x;   // 0..16383
  int hh = idx >> 10, i = idx & 1023;
  float a = 0.f;
  #pragma unroll 8
  for (int d = 0; d < 64; d++) a = fmaf(q[hh * 64 + d], Wk[(size_t)(hh * 64 + d) * DM + i], a);
  qkt[idx] = a * 0.125f;
}

// ---------- head constants: c12[h] = aw.qkt[h]; c12[16+h] = ab.qkt[h] ----------
__global__ void k_c12(const float* __restrict__ qkt, const float* __restrict__ aw,
                      const float* __restrict__ ab, float* __restrict__ c12){
  const int hh = blockIdx.x >> 1, which = blockIdx.x & 1, lane = threadIdx.x;
  const float* src = which ? ab : aw;
  float a = 0.f;
  #pragma unroll
  for (int j = 0; j < 16; j++) a = fmaf(src[lane + 64 * j], qkt[hh * DM + lane + 64 * j], a);
  a = wred(a);
  if (lane == 0) c12[which * NH + hh] = a;
}

// ---------- Qa[h][d] = bf16(qkt[h][d] * aw[d])  (B operand for logits MFMA) ----------
__global__ void k_qa(const float* __restrict__ qkt, const float* __restrict__ aw,
                     unsigned short* __restrict__ Qa){
  const int i = blockIdx.x * 256 + threadIdx.x;   // 16384
  Qa[i] = f2bf(qkt[i] * aw[i & (DM - 1)]);
}

// ---------- geometric bias per (n, head): biasT[n*16+h] ----------
__global__ void k_bias(const float* __restrict__ rbf, const float* __restrict__ seqsep,
                       const float* __restrict__ extra, const float* __restrict__ wbias,
                       float* __restrict__ biasT){
  const int i = blockIdx.x * 256 + threadIdx.x;   // < NN*NH
  const int n = i >> 4, hh = i & 15;
  const float* wb = wbias + hh * 40;
  float bb = 0.f;
  #pragma unroll
  for (int j = 0; j < 16; j++) bb = fmaf(rbf[(size_t)n * 16 + j], wb[j], bb);
  #pragma unroll
  for (int j = 0; j < 4; j++)  bb = fmaf(seqsep[(size_t)n * 4 + j], wb[16 + j], bb);
  #pragma unroll
  for (int j = 0; j < 20; j++) bb = fmaf(extra[(size_t)n * DEX + j], wb[20 + j], bb);
  biasT[i] = bb;
}

// ---------- lean LN pass: wave-per-row, no LDS, no sync, no spill ----------
__global__ void k_lnpass(const float* __restrict__ h, float* __restrict__ meanb,
                         float* __restrict__ rstdb, unsigned short* __restrict__ hbf){
  const int lane = threadIdx.x & 63, w = threadIdx.x >> 6;
  const int gw = blockIdx.x * 4 + w;
  #pragma unroll
  for (int rr = 0; rr < 2; rr++){
    const int n = gw * 2 + rr;
    const float* hp = h + (size_t)n * DM + lane * 16;
    const float4 x0 = *(const float4*)(hp);
    const float4 x1 = *(const float4*)(hp + 4);
    const float4 x2 = *(const float4*)(hp + 8);
    const float4 x3 = *(const float4*)(hp + 12);
    float s  = (x0.x + x0.y + x0.z + x0.w) + (x1.x + x1.y + x1.z + x1.w)
             + (x2.x + x2.y + x2.z + x2.w) + (x3.x + x3.y + x3.z + x3.w);
    float ss = x0.x*x0.x + x0.y*x0.y + x0.z*x0.z + x0.w*x0.w
             + x1.x*x1.x + x1.y*x1.y + x1.z*x1.z + x1.w*x1.w
             + x2.x*x2.x + x2.y*x2.y + x2.z*x2.z + x2.w*x2.w
             + x3.x*x3.x + x3.y*x3.y + x3.z*x3.z + x3.w*x3.w;
    #pragma unroll
    for (int m = 1; m < 64; m <<= 1){ s += __shfl_xor(s, m); ss += __shfl_xor(ss, m); }
    unsigned short* op = hbf + (size_t)n * DM + lane * 16;
    ushort4 o;
    o.x = f2bf(x0.x); o.y = f2bf(x0.y); o.z = f2bf(x0.z); o.w = f2bf(x0.w);
    *(ushort4*)(op) = o;
    o.x = f2bf(x1.x); o.y = f2bf(x1.y); o.z = f2bf(x1.z); o.w = f2bf(x1.w);
    *(ushort4*)(op + 4) = o;
    o.x = f2bf(x2.x); o.y = f2bf(x2.y); o.z = f2bf(x2.z); o.w = f2bf(x2.w);
    *(ushort4*)(op + 8) = o;
    o.x = f2bf(x3.x); o.y = f2bf(x3.y); o.z = f2bf(x3.z); o.w = f2bf(x3.w);
    *(ushort4*)(op + 12) = o;
    if (lane == 0){
      const float mean = s * (1.0f / DM);
      meanb[n] = mean;
      rstdb[n] = rsqrtf(ss * (1.0f / DM) - mean * mean + EPSV);
    }
  }
}

#define MFMA16(a, b, c) __builtin_amdgcn_mfma_f32_16x16x32_bf16(a, b, c, 0, 0, 0)

// ---------- logitsT[n][h] via MFMA: S1 = hbf @ Qa^T, epilogue folds rstd/mean/c12/bias ----------
__launch_bounds__(256)
__global__ void k_logits(const unsigned short* __restrict__ hbf, const unsigned short* __restrict__ Qa,
                         const float* __restrict__ meanb, const float* __restrict__ rstdb,
                         const float* __restrict__ c12, const float* __restrict__ biasT,
                         float* __restrict__ logitsT){
  const int lane = threadIdx.x & 63, w = threadIdx.x >> 6;
  const int n0 = (blockIdx.x * 4 + w) * 16;
  const int fr = lane & 15, kq = lane >> 4;
  f32x4 acc = {0.f, 0.f, 0.f, 0.f};
  const unsigned short* ap = hbf + (size_t)(n0 + fr) * DM + kq * 8;
  const unsigned short* bp = Qa + fr * DM + kq * 8;
  #pragma unroll 4
  for (int kt = 0; kt < DM; kt += 64){
    const bf16x8 a0 = *(const bf16x8*)(ap + kt);
    const bf16x8 b0 = *(const bf16x8*)(bp + kt);
    const bf16x8 a1 = *(const bf16x8*)(ap + kt + 32);
    const bf16x8 b1 = *(const bf16x8*)(bp + kt + 32);
    acc = MFMA16(a0, b0, acc);
    acc = MFMA16(a1, b1, acc);
  }
  const float C1 = c12[fr], C2 = c12[NH + fr];
  #pragma unroll
  for (int r = 0; r < 4; r++){
    const int n = n0 + kq * 4 + r;
    const float mean = meanb[n], rstd = rstdb[n];
    logitsT[(size_t)n * NH + fr] = rstd * acc[r] - rstd * mean * C1 + C2
                                   + biasT[(size_t)n * NH + fr];
  }
}

// ---------- softmax partials over [n][16] layout: 256 blocks ----------
__global__ void k_smpart(const float* __restrict__ logitsT, float* __restrict__ msp){
  const int t = threadIdx.x, lane = t & 63, w = t >> 6;
  const int hh = lane & 15, no = lane >> 4;
  const float* base = logitsT + ((size_t)blockIdx.x * 256 + w * 64) * NH;
  float m = -3.0e38f;
  #pragma unroll
  for (int it = 0; it < 16; it++)
    m = fmaxf(m, base[(it * 4 + no) * NH + hh]);
  m = fmaxf(m, __shfl_xor(m, 16));
  m = fmaxf(m, __shfl_xor(m, 32));
  float s = 0.f;
  #pragma unroll
  for (int it = 0; it < 16; it++)
    s += __expf(base[(it * 4 + no) * NH + hh] - m);
  s += __shfl_xor(s, 16);
  s += __shfl_xor(s, 32);
  __shared__ float sm[4][16], ssm[4][16];
  if (lane < 16){ sm[w][hh] = m; ssm[w][hh] = s; }
  __syncthreads();
  if (t < NH){
    const float M = fmaxf(fmaxf(sm[0][t], sm[1][t]), fmaxf(sm[2][t], sm[3][t]));
    const float S = ssm[0][t] * __expf(sm[0][t] - M) + ssm[1][t] * __expf(sm[1][t] - M)
                  + ssm[2][t] * __expf(sm[2][t] - M) + ssm[3][t] * __expf(sm[3][t] - M);
    msp[((size_t)blockIdx.x * NH + t) * 2]     = M;
    msp[((size_t)blockIdx.x * NH + t) * 2 + 1] = S;
  }
}

__global__ void k_smcomb(const float* __restrict__ msp, float* __restrict__ ms){
  const int lane = threadIdx.x;           // 64
  const int hh = lane & 15, g = lane >> 4;
  float M = -3.0e38f;
  for (int i = g; i < 256; i += 4) M = fmaxf(M, msp[((size_t)i * NH + hh) * 2]);
  M = fmaxf(M, __shfl_xor(M, 16));
  M = fmaxf(M, __shfl_xor(M, 32));
  float S = 0.f;
  for (int i = g; i < 256; i += 4)
    S += msp[((size_t)i * NH + hh) * 2 + 1] * __expf(msp[((size_t)i * NH + hh) * 2] - M);
  S += __shfl_xor(S, 16);
  S += __shfl_xor(S, 32);
  if (lane < NH){ ms[hh] = M; ms[16 + hh] = S; }
}

// ---------- softmax weights: wexp[n][h] = exp(logitsT - m[h]) ----------
__global__ void k_expw(const float* __restrict__ logitsT, const float* __restrict__ ms,
                       float* __restrict__ wexp){
  const int i = blockIdx.x * 256 + threadIdx.x;   // NN*NH/4 float4s
  const float4 v = ((const float4*)logitsT)[i];
  const int hb = (i & 3) * 4;
  float4 o;
  o.x = __expf(v.x - ms[hb]);
  o.y = __expf(v.y - ms[hb + 1]);
  o.z = __expf(v.z - ms[hb + 2]);
  o.w = __expf(v.w - ms[hb + 3]);
  ((float4*)wexp)[i] = o;
}

// ---------- u partials: upart[b,hh,d] = sum_rows wexp * LN(h) ----------
#define UB 256
__global__ void k_upart(const unsigned short* __restrict__ hbf, const float* __restrict__ meanb,
                        const float* __restrict__ rstdb, const float* __restrict__ aw,
                        const float* __restrict__ ab, const float* __restrict__ wexp,
                        float* __restrict__ upart){
  const int t = threadIdx.x, bb = blockIdx.x;
  const float4 w  = *(const float4*)(aw + t * 4);
  const float4 bv = *(const float4*)(ab + t * 4);
  float acc[NH][4];
  #pragma unroll
  for (int hh = 0; hh < NH; hh++){ acc[hh][0] = 0.f; acc[hh][1] = 0.f; acc[hh][2] = 0.f; acc[hh][3] = 0.f; }
  #pragma unroll 2
  for (int r = 0; r < NN / UB; r++){
    const int n = bb * (NN / UB) + r;
    const float mean = meanb[n], rstd = rstdb[n];
    const ushort4 hb = *(const ushort4*)(hbf + (size_t)n * DM + t * 4);
    const float l0 = (bf2f(hb.x) - mean) * rstd * w.x + bv.x;
    const float l1 = (bf2f(hb.y) - mean) * rstd * w.y + bv.y;
    const float l2 = (bf2f(hb.z) - mean) * rstd * w.z + bv.z;
    const float l3 = (bf2f(hb.w) - mean) * rstd * w.w + bv.w;
    const float4 e0 = *(const float4*)(wexp + (size_t)n * NH);
    const float4 e1 = *(const float4*)(wexp + (size_t)n * NH + 4);
    const float4 e2 = *(const float4*)(wexp + (size_t)n * NH + 8);
    const float4 e3 = *(const float4*)(wexp + (size_t)n * NH + 12);
#define ACC1(h, e) { acc[h][0] = fmaf(e, l0, acc[h][0]); acc[h][1] = fmaf(e, l1, acc[h][1]); \
                     acc[h][2] = fmaf(e, l2, acc[h][2]); acc[h][3] = fmaf(e, l3, acc[h][3]); }
    ACC1(0, e0.x)  ACC1(1, e0.y)  ACC1(2, e0.z)  ACC1(3, e0.w)
    ACC1(4, e1.x)  ACC1(5, e1.y)  ACC1(6, e1.z)  ACC1(7, e1.w)
    ACC1(8, e2.x)  ACC1(9, e2.y)  ACC1(10, e2.z) ACC1(11, e2.w)
    ACC1(12, e3.x) ACC1(13, e3.y) ACC1(14, e3.z) ACC1(15, e3.w)
#undef ACC1
  }
  #pragma unroll
  for (int hh = 0; hh < NH; hh++){
    float4 o; o.x = acc[hh][0]; o.y = acc[hh][1]; o.z = acc[hh][2]; o.w = acc[hh][3];
    *(float4*)(upart + ((size_t)bb * NH + hh) * DM + t * 4) = o;
  }
}

// ---------- two-level reduce of upart ----------
__global__ void k_ured1(const float* __restrict__ upart, float* __restrict__ up2){
  const int idx = (blockIdx.x & 63) * 256 + threadIdx.x;   // 0..16383
  const int sl  = blockIdx.x >> 6;                          // 0..15
  float s = 0.f;
  for (int b = sl * 16; b < sl * 16 + 16; b++) s += upart[(size_t)b * (NH * DM) + idx];
  up2[(size_t)sl * (NH * DM) + idx] = s;
}

__global__ void k_ured2(const float* __restrict__ up2, const float* __restrict__ ms,
                        float* __restrict__ u){
  const int idx = blockIdx.x * 256 + threadIdx.x;   // 0..16383
  const int hh = idx >> 10;
  float s = 0.f;
  #pragma unroll
  for (int sl = 0; sl < 16; sl++) s += up2[(size_t)sl * (NH * DM) + idx];
  u[idx] = s / ms[16 + hh];
}

// ---------- out_center[o] = u[head(o),:] . Wv[o,:] ----------
__global__ void k_oc(const float* __restrict__ u, const float* __restrict__ Wv,
                     float* __restrict__ oc){
  int lane = threadIdx.x & 63, wid = threadIdx.x >> 6;
  #pragma unroll
  for (int oi = 0; oi < 4; oi++){
    int o = blockIdx.x * 16 + wid * 4 + oi;
    const float* ur = u + (size_t)(o >> 6) * DM;
    const float* wr = Wv + (size_t)o * DM;
    float a = 0.f;
    #pragma unroll
    for (int j = 0; j < 16; j++) a = fmaf(ur[lane + 64 * j], wr[lane + 64 * j], a);
    a = wred(a);
    if (lane == 0) oc[o] = a;
  }
}

// ---------- hcnew[o] = h[c,o] + 0.5 * oc . Wo[o,:] ----------
__global__ void k_delta(const float* __restrict__ oc, const float* __restrict__ Wo,
                        const float* __restrict__ h, const int* __restrict__ cidx,
                        float* __restrict__ hcnew){
  int lane = threadIdx.x & 63, wid = threadIdx.x >> 6;
  int c = *cidx;
  float ov[16];
  #pragma unroll
  for (int j = 0; j < 16; j++) ov[j] = oc[lane + 64 * j];
  #pragma unroll
  for (int oi = 0; oi < 4; oi++){
    int o = blockIdx.x * 16 + wid * 4 + oi;
    const float* wr = Wo + (size_t)o * DM;
    float a = 0.f;
    #pragma unroll
    for (int j = 0; j < 16; j++) a = fmaf(ov[j], wr[lane + 64 * j], a);
    a = wred(a);
    if (lane == 0) hcnew[o] = h[(size_t)c * DM + o] + 0.5f * a;
  }
}

// ---------- rank-1 column biases: gbtot/fbtot ----------
__global__ void k_gbfb(const float* __restrict__ hcnew, const float* __restrict__ gateW,
                       const float* __restrict__ gateB, const float* __restrict__ fuseW1,
                       const float* __restrict__ fuseB1, float* __restrict__ gbtot,
                       float* __restrict__ fbtot){
  int lane = threadIdx.x & 63, wid = threadIdx.x >> 6;
  float hv[16];
  #pragma unroll
  for (int j = 0; j < 16; j++) hv[j] = hcnew[lane + 64 * j];
  #pragma unroll
  for (int oi = 0; oi < 4; oi++){
    int o = blockIdx.x * 16 + wid * 4 + oi;
    const float* gr = gateW + (size_t)o * 2048 + 1024;
    const float* fr = fuseW1 + (size_t)o * 2048 + 1024;
    float ga = 0.f, fa = 0.f;
    #pragma unroll
    for (int j = 0; j < 16; j++){
      ga = fmaf(hv[j], gr[lane + 64 * j], ga);
      fa = fmaf(hv[j], fr[lane + 64 * j], fa);
    }
    ga = wred(ga); fa = wred(fa);
    if (lane == 0){ gbtot[o] = ga + gateB[o]; fbtot[o] = fa + fuseB1[o]; }
  }
}

// ---------- MFMA GEMM, 256x256 tile, BK=64, 8-phase counted-vmcnt, asm ds_read ----------
// r10 structure (best: 452 us MODE0) + FULL K-loop unroll: all stage kt offsets and
// &15 wraps become compile-time constants -> per-phase address VALU collapses to
// loop-invariant base + immediate. Schedule/ledger unchanged.
#define BM 256
#define BK 64
#define H128 ((size_t)128 * DM)
#define GLL16(gp, lp) __builtin_amdgcn_global_load_lds((const __attribute__((address_space(1))) void*)(gp), (__attribute__((address_space(3))) void*)(lp), 16, 0, 0)
#define SBAR() do { __builtin_amdgcn_sched_barrier(0); \
                    asm volatile("s_barrier" ::: "memory"); \
                    __builtin_amdgcn_sched_barrier(0); } while (0)

#define PHASE(BUF, Q, STG, STL, STK, DOVM) do {                                        \
    if ((Q) == 0){                                                                     \
      _Pragma("unroll")                                                                \
      for (int nj = 0; nj < 4; nj++){                                                  \
        bq[nj][0] = ldsr128(lB + (BUF)*16384 + bBase + nj*1024 + kOff0);               \
        bq[nj][1] = ldsr128(lB + (BUF)*16384 + bBase + nj*1024 + kOff1);               \
      }                                                                                \
    }                                                                                  \
    bf16x8 a00 = ldsr128(lA + (BUF)*16384 + aBase + (2*(Q))*1024   + kOff0);           \
    bf16x8 a01 = ldsr128(lA + (BUF)*16384 + aBase + (2*(Q))*1024   + kOff1);           \
    bf16x8 a10 = ldsr128(lA + (BUF)*16384 + aBase + (2*(Q)+1)*1024 + kOff0);           \
    bf16x8 a11 = ldsr128(lA + (BUF)*16384 + aBase + (2*(Q)+1)*1024 + kOff1);           \
    stage(STG, STL, STK);                                                              \
    SBAR();                                                                            \
    asm volatile("s_waitcnt lgkmcnt(0)" ::: "memory");                                 \
    __builtin_amdgcn_sched_barrier(0);                                                 \
    __builtin_amdgcn_s_setprio(1);                                                     \
    _Pragma("unroll")                                                                  \
    for (int nj = 0; nj < 4; nj++){                                                    \
      acc[2*(Q)][nj]   = MFMA16(a00, bq[nj][0], acc[2*(Q)][nj]);                       \
      acc[2*(Q)][nj]   = MFMA16(a01, bq[nj][1], acc[2*(Q)][nj]);                       \
      acc[2*(Q)+1][nj] = MFMA16(a10, bq[nj][0], acc[2*(Q)+1][nj]);                     \
      acc[2*(Q)+1][nj] = MFMA16(a11, bq[nj][1], acc[2*(Q)+1][nj]);                     \
    }                                                                                  \
    __builtin_amdgcn_s_setprio(0);                                                     \
    if (DOVM){ asm volatile("s_waitcnt vmcnt(4)" ::: "memory"); }                      \
    SBAR();                                                                            \
  } while (0)

template<int MODE>
__launch_bounds__(512, 2)
__global__ void k_gemm(const unsigned short* __restrict__ A, const unsigned short* __restrict__ B,
                       const float* __restrict__ bias0, const float* __restrict__ bias1,
                       const unsigned short* __restrict__ hsrcb, const unsigned short* __restrict__ gate,
                       unsigned short* __restrict__ og, unsigned short* __restrict__ ot,
                       float* __restrict__ of){
  __shared__ __attribute__((aligned(16))) unsigned short lA[32768];
  __shared__ __attribute__((aligned(16))) unsigned short lB[32768];
  const int NWG = (MODE == 0) ? 2048 : 1024;
  const int NYT = (MODE == 0) ? 8 : 4;
  const int bid = blockIdx.x;
  const int remap = (bid & 7) * (NWG >> 3) + (bid >> 3);
  const int m0 = (remap / NYT) * BM, n0 = (remap % NYT) * BM;

  const int tid = threadIdx.x, lane = tid & 63, w = tid >> 6;
  const int wm = w >> 2, wn = w & 3;

  f32x4 acc[8][4];
  #pragma unroll
  for (int i = 0; i < 8; i++){
    #pragma unroll
    for (int j = 0; j < 4; j++){ acc[i][j][0] = 0.f; acc[i][j][1] = 0.f; acc[i][j][2] = 0.f; acc[i][j][3] = 0.f; }
  }

  const int ln3 = lane >> 3;
  const size_t stRow0 = (size_t)(w * 16 + ln3);
  const int sxor = ((lane & 7) ^ ln3) * 8;
  const size_t srcOff0 = stRow0 * DM + sxor;
  const size_t srcOff1 = (stRow0 + 8) * DM + sxor;
  const int dst0 = w * 1024 + lane * 8;
  const int dst1 = dst0 + 512;

  const unsigned short* gA = A + (size_t)m0 * DM;
  const unsigned short* gB = B + (size_t)n0 * DM;

  auto stage = [&](const unsigned short* g, unsigned short* ldsr, int kt){
    GLL16(g + srcOff0 + kt * 64, ldsr + dst0);
    GLL16(g + srcOff1 + kt * 64, ldsr + dst1);
  };

  const int fr = lane & 15;
  const int kq = lane >> 4;
  const int kOff0 = ((kq)     ^ (lane & 7)) * 8;
  const int kOff1 = ((4 + kq) ^ (lane & 7)) * 8;
  const int aBase = wm * 8192 + fr * 64;
  const int bBase = (wn >> 1) * 8192 + ((wn & 1) * 64 + fr) * 64;

  bf16x8 bq[4][2];

  stage(gA,        lA,                0);
  stage(gA + H128, lA + 8192,         0);
  stage(gB,        lB,                0);
  stage(gB + H128, lB + 8192,         0);
  stage(gB,        lB + 16384,        1);
  stage(gB + H128, lB + 16384 + 8192, 1);
  asm volatile("s_waitcnt vmcnt(4)" ::: "memory");
  SBAR();

  #pragma unroll
  for (int i = 0; i < 8; i++){
    const int k0 = 2 * i;
    PHASE(0, 0, gA,        lA + 16384,        k0 + 1,        false);
    PHASE(0, 1, gA + H128, lA + 16384 + 8192, k0 + 1,        false);
    PHASE(0, 2, gB,        lB,                (k0 + 2) & 15, false);
    PHASE(0, 3, gB + H128, lB + 8192,         (k0 + 2) & 15, true);
    PHASE(1, 0, gA,        lA,                (k0 + 2) & 15, false);
    PHASE(1, 1, gA + H128, lA + 8192,         (k0 + 2) & 15, false);
    PHASE(1, 2, gB,        lB + 16384,        (k0 + 3) & 15, false);
    PHASE(1, 3, gB + H128, lB + 16384 + 8192, (k0 + 3) & 15, true);
  }

  const int r0 = kq * 4;
  #pragma unroll
  for (int mi = 0; mi < 8; mi++){
    #pragma unroll
    for (int nj = 0; nj < 4; nj++){
      const int gmb = m0 + wm * 128 + mi * 16 + r0;
      const int gn  = n0 + wn * 64 + nj * 16 + fr;
      #pragma unroll
      for (int r = 0; r < 4; r++){
        const int gm = gmb + r;
        const float x = acc[mi][nj][r];
        if (MODE == 0){
          if (gn < 1024){
            const float v = x + bias0[gn];
            og[(size_t)gm * DM + gn] = f2bf(1.0f / (1.0f + __expf(-v)));
          } else {
            const float v = x + bias1[gn - 1024];
            ot[(size_t)gm * DM + (gn - 1024)] = f2bf(v / (1.0f + __expf(-v)));
          }
        } else {
          const float v = x + bias0[gn];
          const float g = bf2f(gate[(size_t)gm * DM + gn]);
          of[(size_t)gm * DM + gn] = bf2f(hsrcb[(size_t)gm * DM + gn]) + 0.5f * g * v;
        }
      }
    }
  }
}

// ---------- overwrite center row ----------
__global__ void k_fixc(const float* __restrict__ hcnew, const int* __restrict__ cidx,
                       float* __restrict__ out){
  int t = threadIdx.x;
  int c = *cidx;
  out[(size_t)c * DM + t] = hcnew[t];
}

extern "C" void kernel_launch(void* const* d_in, const int* in_sizes, int n_in,
                              void* d_out, int out_size, void* d_ws, size_t ws_size,
                              hipStream_t stream){
  const float* h      = (const float*)d_in[0];
  const float* rbf    = (const float*)d_in[1];
  const float* seqsep = (const float*)d_in[2];
  const float* localb = (const float*)d_in[3];
  const float* ncw    = (const float*)d_in[4];
  const float* ncb    = (const float*)d_in[5];
  const float* naw    = (const float*)d_in[6];
  const float* nab    = (const float*)d_in[7];
  const float* Wq     = (const float*)d_in[8];
  const float* Wk     = (const float*)d_in[9];
  const float* Wv     = (const float*)d_in[10];
  const float* Wo     = (const float*)d_in[11];
  const float* Wbias  = (const float*)d_in[12];
  const float* gateW  = (const float*)d_in[13];
  const float* gateB  = (const float*)d_in[14];
  const float* fuseW1 = (const float*)d_in[15];
  const float* fuseB1 = (const float*)d_in[16];
  const float* fuseW2 = (const float*)d_in[17];
  const float* fuseB2 = (const float*)d_in[18];
  const int*   nbr    = (const int*)d_in[19];
  const int*   cidx   = (const int*)d_in[20];
  float* out = (float*)d_out;

  char* p = (char*)d_ws;
  auto alloc = [&](size_t nb){ char* r = p; p += (nb + 255) & ~(size_t)255; return r; };
  float* extra   = (float*)alloc((size_t)NN * DEX * 4);
  float* logitsT = (float*)alloc((size_t)NN * NH * 4);
  float* wexp    = (float*)alloc((size_t)NN * NH * 4);
  float* biasT   = (float*)alloc((size_t)NN * NH * 4);
  float* meanb   = (float*)alloc((size_t)NN * 4);
  float* rstdb   = (float*)alloc((size_t)NN * 4);
  float* ms      = (float*)alloc(32 * 4);
  float* msp     = (float*)alloc((size_t)256 * NH * 2 * 4);
  float* qkt     = (float*)alloc(NH * DM * 4);
  float* u       = (float*)alloc(NH * DM * 4);
  float* hcln    = (float*)alloc(DM * 4);
  float* qv      = (float*)alloc(DM * 4);
  float* oc      = (float*)alloc(DM * 4);
  float* hcnew   = (float*)alloc(DM * 4);
  float* gbtot   = (float*)alloc(DM * 4);
  float* fbtot   = (float*)alloc(DM * 4);
  float* c12     = (float*)alloc(32 * 4);
  float* up2     = (float*)alloc((size_t)16 * NH * DM * 4);
  float* upart   = (float*)alloc((size_t)UB * NH * DM * 4);
  unsigned short* Wcomb = (unsigned short*)alloc((size_t)2048 * 1024 * 2);
  unsigned short* W2b   = (unsigned short*)alloc((size_t)1024 * 1024 * 2);
  unsigned short* Qa    = (unsigned short*)alloc((size_t)NH * DM * 2);
  unsigned short* hbf   = (unsigned short*)alloc((size_t)NN * DM * 2);
  unsigned short* gateb = (unsigned short*)alloc((size_t)NN * DM * 2);
  unsigned short* t1    = (unsigned short*)alloc((size_t)NN * DM * 2);
  if ((size_t)(p - (char*)d_ws) > ws_size) return;  // clean fail instead of corruption

  hipMemsetAsync(extra, 0, (size_t)NN * DEX * 4, stream);
  k_scatter<<<(KNB * DEX + 255) / 256, 256, 0, stream>>>(localb, nbr, extra);
  k_convw<<<(3 * 1024 * 1024) / 256, 256, 0, stream>>>(gateW, fuseW1, fuseW2, Wcomb, W2b);
  k_cln<<<1, 256, 0, stream>>>(h, cidx, ncw, ncb, hcln);
  k_q<<<64, 256, 0, stream>>>(hcln, Wq, qv);
  k_qkt<<<64, 256, 0, stream>>>(qv, Wk, qkt);
  k_c12<<<32, 64, 0, stream>>>(qkt, naw, nab, c12);
  k_qa<<<64, 256, 0, stream>>>(qkt, naw, Qa);
  k_bias<<<NN * NH / 256, 256, 0, stream>>>(rbf, seqsep, extra, Wbias, biasT);
  k_lnpass<<<NN / 8, 256, 0, stream>>>(h, meanb, rstdb, hbf);
  k_logits<<<1024, 256, 0, stream>>>(hbf, Qa, meanb, rstdb, c12, biasT, logitsT);
  k_smpart<<<256, 256, 0, stream>>>(logitsT, msp);
  k_smcomb<<<1, 64, 0, stream>>>(msp, ms);
  k_expw<<<NN * NH / 4 / 256, 256, 0, stream>>>(logitsT, ms, wexp);
  k_upart<<<UB, 256, 0, stream>>>(hbf, meanb, rstdb, naw, nab, wexp, upart);
  k_ured1<<<1024, 256, 0, stream>>>(upart, up2);
  k_ured2<<<64, 256, 0, stream>>>(up2, ms, u);
  k_oc<<<64, 256, 0, stream>>>(u, Wv, oc);
  k_delta<<<64, 256, 0, stream>>>(oc, Wo, h, cidx, hcnew);
  k_gbfb<<<64, 256, 0, stream>>>(hcnew, gateW, gateB, fuseW1, fuseB1, gbtot, fbtot);
  k_gemm<0><<<2048, 512, 0, stream>>>(hbf, Wcomb, gbtot, fbtot, nullptr, nullptr, gateb, t1, nullptr);
  k_gemm<1><<<1024, 512, 0, stream>>>(t1, W2b, fuseB2, nullptr, hbf, gateb, nullptr, nullptr, out);
  k_fixc<<<1, 1024, 0, stream>>>(hcnew, cidx, out);
}

// Round 13
// 925.125 us; speedup vs baseline: 1.0878x; 1.0340x over previous
//
#include <hip/hip_runtime.h>
#include <hip/hip_bf16.h>

#define NN 65536
#define DM 1024
#define NH 16
#define KNB 4096
#define DEX 20
#define EPSV 1e-5f

typedef __attribute__((ext_vector_type(8))) short bf16x8;
typedef __attribute__((ext_vector_type(4))) float f32x4;

__device__ __forceinline__ unsigned short f2bf(float f){
  unsigned u = __builtin_bit_cast(unsigned, f);
  u += 0x7fffu + ((u >> 16) & 1u);
  return (unsigned short)(u >> 16);
}
__device__ __forceinline__ float bf2f(unsigned short s){
  return __builtin_bit_cast(float, ((unsigned)s) << 16);
}
__device__ __forceinline__ float wred(float v){
  #pragma unroll
  for (int s = 32; s; s >>= 1) v += __shfl_down(v, s);
  return v;
}

// opaque LDS read: compiler cannot see this is an LDS access -> inserts NO
// hazard waits; we own all waits (lgkmcnt(0)+sched_barrier per rule #18).
__device__ __forceinline__ bf16x8 ldsr128(const unsigned short* p){
  bf16x8 r;
  unsigned a = (unsigned)(size_t)(const __attribute__((address_space(3))) void*)p;
  asm volatile("ds_read_b128 %0, %1" : "=v"(r) : "v"(a));
  return r;
}

// ---------- scatter local_bias rows into extra (N x 20); extra pre-zeroed ----------
__global__ void k_scatter(const float* __restrict__ lb, const int* __restrict__ nidx,
                          float* __restrict__ extra){
  int i = blockIdx.x * 256 + threadIdx.x;
  if (i < KNB * DEX){
    int j = i / DEX, col = i - j * DEX;
    extra[(size_t)nidx[j] * DEX + col] = lb[i];
  }
}

// ---------- convert MLP weights to bf16: Wcomb (2048x1024) + W2b (1024x1024) ----------
__global__ void k_convw(const float* __restrict__ gateW, const float* __restrict__ fuseW1,
                        const float* __restrict__ fuseW2,
                        unsigned short* __restrict__ Wcomb, unsigned short* __restrict__ W2b){
  int i = blockIdx.x * 256 + threadIdx.x;
  if (i < 2048 * 1024){
    int o = i >> 10, d = i & 1023;
    float v = (o < 1024) ? gateW[(size_t)o * 2048 + d] : fuseW1[(size_t)(o - 1024) * 2048 + d];
    Wcomb[i] = f2bf(v);
  } else {
    int j = i - 2048 * 1024;
    W2b[j] = f2bf(fuseW2[j]);
  }
}

// ---------- LN of center row (norm_c) -> hcln[1024] ----------
__global__ void k_cln(const float* __restrict__ h, const int* __restrict__ cidx,
                      const float* __restrict__ cw, const float* __restrict__ cb,
                      float* __restrict__ hcln){
  int t = threadIdx.x, lane = t & 63, wid = t >> 6;
  int c = *cidx;
  const float4 x = *(const float4*)(h + (size_t)c * DM + t * 4);
  float s  = x.x + x.y + x.z + x.w;
  float ss = x.x * x.x + x.y * x.y + x.z * x.z + x.w * x.w;
  __shared__ float rs[4], rq[4];
  s = wred(s); ss = wred(ss);
  if (lane == 0){ rs[wid] = s; rq[wid] = ss; }
  __syncthreads();
  float mean = (rs[0] + rs[1] + rs[2] + rs[3]) * (1.0f / DM);
  float var  = (rq[0] + rq[1] + rq[2] + rq[3]) * (1.0f / DM) - mean * mean;
  float rstd = rsqrtf(var + EPSV);
  const float4 w = *(const float4*)(cw + t * 4);
  const float4 b = *(const float4*)(cb + t * 4);
  float4 o;
  o.x = (x.x - mean) * rstd * w.x + b.x;
  o.y = (x.y - mean) * rstd * w.y + b.y;
  o.z = (x.z - mean) * rstd * w.z + b.z;
  o.w = (x.w - mean) * rstd * w.w + b.w;
  *(float4*)(hcln + t * 4) = o;
}

// ---------- q[o] = hcln . Wq[o,:] ----------
__global__ void k_q(const float* __restrict__ hcln, const float* __restrict__ Wq,
                    float* __restrict__ q){
  int lane = threadIdx.x & 63, wid = threadIdx.x >> 6;
  float hv[16];
  #pragma unroll
  for (int j = 0; j < 16; j++) hv[j] = hcln[lane + 64 * j];
  #pragma unroll
  for (int oi = 0; oi < 4; oi++){
    int o = blockIdx.x * 16 + wid * 4 + oi;
    const float* wr = Wq + (size_t)o * DM;
    float a = 0.f;
    #pragma unroll
    for (int j = 0; j < 16; j++) a = fmaf(hv[j], wr[lane + 64 * j], a);
    a = wred(a);
    if (lane == 0) q[o] = a;
  }
}

// ---------- qkt[hh,i] = (sum_d q[hh*64+d] * Wk[hh*64+d, i]) / 8 ----------
__global__ void k_qkt(const float* __restrict__ q, const float* __restrict__ Wk,
                      float* __restrict__ qkt){
  int idx = blockIdx.x * 256 + threadIdx.x;   // 0..16383
  int hh = idx >> 10, i = idx & 1023;
  float a = 0.f;
  #pragma unroll 8
  for (int d = 0; d < 64; d++) a = fmaf(q[hh * 64 + d], Wk[(size_t)(hh * 64 + d) * DM + i], a);
  qkt[idx] = a * 0.125f;
}

// ---------- head constants: c12[h] = aw.qkt[h]; c12[16+h] = ab.qkt[h] ----------
__global__ void k_c12(const float* __restrict__ qkt, const float* __restrict__ aw,
                      const float* __restrict__ ab, float* __restrict__ c12){
  const int hh = blockIdx.x >> 1, which = blockIdx.x & 1, lane = threadIdx.x;
  const float* src = which ? ab : aw;
  float a = 0.f;
  #pragma unroll
  for (int j = 0; j < 16; j++) a = fmaf(src[lane + 64 * j], qkt[hh * DM + lane + 64 * j], a);
  a = wred(a);
  if (lane == 0) c12[which * NH + hh] = a;
}

// ---------- Qa[h][d] = bf16(qkt[h][d] * aw[d])  (B operand for logits MFMA) ----------
__global__ void k_qa(const float* __restrict__ qkt, const float* __restrict__ aw,
                     unsigned short* __restrict__ Qa){
  const int i = blockIdx.x * 256 + threadIdx.x;   // 16384
  Qa[i] = f2bf(qkt[i] * aw[i & (DM - 1)]);
}

// ---------- geometric bias per (n, head): biasT[n*16+h] ----------
__global__ void k_bias(const float* __restrict__ rbf, const float* __restrict__ seqsep,
                       const float* __restrict__ extra, const float* __restrict__ wbias,
                       float* __restrict__ biasT){
  const int i = blockIdx.x * 256 + threadIdx.x;   // < NN*NH
  const int n = i >> 4, hh = i & 15;
  const float* wb = wbias + hh * 40;
  float bb = 0.f;
  #pragma unroll
  for (int j = 0; j < 16; j++) bb = fmaf(rbf[(size_t)n * 16 + j], wb[j], bb);
  #pragma unroll
  for (int j = 0; j < 4; j++)  bb = fmaf(seqsep[(size_t)n * 4 + j], wb[16 + j], bb);
  #pragma unroll
  for (int j = 0; j < 20; j++) bb = fmaf(extra[(size_t)n * DEX + j], wb[20 + j], bb);
  biasT[i] = bb;
}

// ---------- lean LN pass: wave-per-row, no LDS, no sync, no spill ----------
__global__ void k_lnpass(const float* __restrict__ h, float* __restrict__ meanb,
                         float* __restrict__ rstdb, unsigned short* __restrict__ hbf){
  const int lane = threadIdx.x & 63, w = threadIdx.x >> 6;
  const int gw = blockIdx.x * 4 + w;
  #pragma unroll
  for (int rr = 0; rr < 2; rr++){
    const int n = gw * 2 + rr;
    const float* hp = h + (size_t)n * DM + lane * 16;
    const float4 x0 = *(const float4*)(hp);
    const float4 x1 = *(const float4*)(hp + 4);
    const float4 x2 = *(const float4*)(hp + 8);
    const float4 x3 = *(const float4*)(hp + 12);
    float s  = (x0.x + x0.y + x0.z + x0.w) + (x1.x + x1.y + x1.z + x1.w)
             + (x2.x + x2.y + x2.z + x2.w) + (x3.x + x3.y + x3.z + x3.w);
    float ss = x0.x*x0.x + x0.y*x0.y + x0.z*x0.z + x0.w*x0.w
             + x1.x*x1.x + x1.y*x1.y + x1.z*x1.z + x1.w*x1.w
             + x2.x*x2.x + x2.y*x2.y + x2.z*x2.z + x2.w*x2.w
             + x3.x*x3.x + x3.y*x3.y + x3.z*x3.z + x3.w*x3.w;
    #pragma unroll
    for (int m = 1; m < 64; m <<= 1){ s += __shfl_xor(s, m); ss += __shfl_xor(ss, m); }
    unsigned short* op = hbf + (size_t)n * DM + lane * 16;
    ushort4 o;
    o.x = f2bf(x0.x); o.y = f2bf(x0.y); o.z = f2bf(x0.z); o.w = f2bf(x0.w);
    *(ushort4*)(op) = o;
    o.x = f2bf(x1.x); o.y = f2bf(x1.y); o.z = f2bf(x1.z); o.w = f2bf(x1.w);
    *(ushort4*)(op + 4) = o;
    o.x = f2bf(x2.x); o.y = f2bf(x2.y); o.z = f2bf(x2.z); o.w = f2bf(x2.w);
    *(ushort4*)(op + 8) = o;
    o.x = f2bf(x3.x); o.y = f2bf(x3.y); o.z = f2bf(x3.z); o.w = f2bf(x3.w);
    *(ushort4*)(op + 12) = o;
    if (lane == 0){
      const float mean = s * (1.0f / DM);
      meanb[n] = mean;
      rstdb[n] = rsqrtf(ss * (1.0f / DM) - mean * mean + EPSV);
    }
  }
}

#define MFMA16(a, b, c) __builtin_amdgcn_mfma_f32_16x16x32_bf16(a, b, c, 0, 0, 0)

// ---------- logitsT[n][h] via MFMA: S1 = hbf @ Qa^T, epilogue folds rstd/mean/c12/bias ----------
__launch_bounds__(256)
__global__ void k_logits(const unsigned short* __restrict__ hbf, const unsigned short* __restrict__ Qa,
                         const float* __restrict__ meanb, const float* __restrict__ rstdb,
                         const float* __restrict__ c12, const float* __restrict__ biasT,
                         float* __restrict__ logitsT){
  const int lane = threadIdx.x & 63, w = threadIdx.x >> 6;
  const int n0 = (blockIdx.x * 4 + w) * 16;
  const int fr = lane & 15, kq = lane >> 4;
  f32x4 acc = {0.f, 0.f, 0.f, 0.f};
  const unsigned short* ap = hbf + (size_t)(n0 + fr) * DM + kq * 8;
  const unsigned short* bp = Qa + fr * DM + kq * 8;
  #pragma unroll 4
  for (int kt = 0; kt < DM; kt += 64){
    const bf16x8 a0 = *(const bf16x8*)(ap + kt);
    const bf16x8 b0 = *(const bf16x8*)(bp + kt);
    const bf16x8 a1 = *(const bf16x8*)(ap + kt + 32);
    const bf16x8 b1 = *(const bf16x8*)(bp + kt + 32);
    acc = MFMA16(a0, b0, acc);
    acc = MFMA16(a1, b1, acc);
  }
  const float C1 = c12[fr], C2 = c12[NH + fr];
  #pragma unroll
  for (int r = 0; r < 4; r++){
    const int n = n0 + kq * 4 + r;
    const float mean = meanb[n], rstd = rstdb[n];
    logitsT[(size_t)n * NH + fr] = rstd * acc[r] - rstd * mean * C1 + C2
                                   + biasT[(size_t)n * NH + fr];
  }
}

// ---------- softmax partials over [n][16] layout: 256 blocks ----------
__global__ void k_smpart(const float* __restrict__ logitsT, float* __restrict__ msp){
  const int t = threadIdx.x, lane = t & 63, w = t >> 6;
  const int hh = lane & 15, no = lane >> 4;
  const float* base = logitsT + ((size_t)blockIdx.x * 256 + w * 64) * NH;
  float m = -3.0e38f;
  #pragma unroll
  for (int it = 0; it < 16; it++)
    m = fmaxf(m, base[(it * 4 + no) * NH + hh]);
  m = fmaxf(m, __shfl_xor(m, 16));
  m = fmaxf(m, __shfl_xor(m, 32));
  float s = 0.f;
  #pragma unroll
  for (int it = 0; it < 16; it++)
    s += __expf(base[(it * 4 + no) * NH + hh] - m);
  s += __shfl_xor(s, 16);
  s += __shfl_xor(s, 32);
  __shared__ float sm[4][16], ssm[4][16];
  if (lane < 16){ sm[w][hh] = m; ssm[w][hh] = s; }
  __syncthreads();
  if (t < NH){
    const float M = fmaxf(fmaxf(sm[0][t], sm[1][t]), fmaxf(sm[2][t], sm[3][t]));
    const float S = ssm[0][t] * __expf(sm[0][t] - M) + ssm[1][t] * __expf(sm[1][t] - M)
                  + ssm[2][t] * __expf(sm[2][t] - M) + ssm[3][t] * __expf(sm[3][t] - M);
    msp[((size_t)blockIdx.x * NH + t) * 2]     = M;
    msp[((size_t)blockIdx.x * NH + t) * 2 + 1] = S;
  }
}

__global__ void k_smcomb(const float* __restrict__ msp, float* __restrict__ ms){
  const int lane = threadIdx.x;           // 64
  const int hh = lane & 15, g = lane >> 4;
  float M = -3.0e38f;
  for (int i = g; i < 256; i += 4) M = fmaxf(M, msp[((size_t)i * NH + hh) * 2]);
  M = fmaxf(M, __shfl_xor(M, 16));
  M = fmaxf(M, __shfl_xor(M, 32));
  float S = 0.f;
  for (int i = g; i < 256; i += 4)
    S += msp[((size_t)i * NH + hh) * 2 + 1] * __expf(msp[((size_t)i * NH + hh) * 2] - M);
  S += __shfl_xor(S, 16);
  S += __shfl_xor(S, 32);
  if (lane < NH){ ms[hh] = M; ms[16 + hh] = S; }
}

// ---------- softmax weights: wexp[n][h] = exp(logitsT - m[h]) ----------
__global__ void k_expw(const float* __restrict__ logitsT, const float* __restrict__ ms,
                       float* __restrict__ wexp){
  const int i = blockIdx.x * 256 + threadIdx.x;   // NN*NH/4 float4s
  const float4 v = ((const float4*)logitsT)[i];
  const int hb = (i & 3) * 4;
  float4 o;
  o.x = __expf(v.x - ms[hb]);
  o.y = __expf(v.y - ms[hb + 1]);
  o.z = __expf(v.z - ms[hb + 2]);
  o.w = __expf(v.w - ms[hb + 3]);
  ((float4*)wexp)[i] = o;
}

// ---------- u partials: upart[b,hh,d] = sum_rows wexp * LN(h) ----------
#define UB 256
__global__ void k_upart(const unsigned short* __restrict__ hbf, const float* __restrict__ meanb,
                        const float* __restrict__ rstdb, const float* __restrict__ aw,
                        const float* __restrict__ ab, const float* __restrict__ wexp,
                        float* __restrict__ upart){
  const int t = threadIdx.x, bb = blockIdx.x;
  const float4 w  = *(const float4*)(aw + t * 4);
  const float4 bv = *(const float4*)(ab + t * 4);
  float acc[NH][4];
  #pragma unroll
  for (int hh = 0; hh < NH; hh++){ acc[hh][0] = 0.f; acc[hh][1] = 0.f; acc[hh][2] = 0.f; acc[hh][3] = 0.f; }
  #pragma unroll 2
  for (int r = 0; r < NN / UB; r++){
    const int n = bb * (NN / UB) + r;
    const float mean = meanb[n], rstd = rstdb[n];
    const ushort4 hb = *(const ushort4*)(hbf + (size_t)n * DM + t * 4);
    const float l0 = (bf2f(hb.x) - mean) * rstd * w.x + bv.x;
    const float l1 = (bf2f(hb.y) - mean) * rstd * w.y + bv.y;
    const float l2 = (bf2f(hb.z) - mean) * rstd * w.z + bv.z;
    const float l3 = (bf2f(hb.w) - mean) * rstd * w.w + bv.w;
    const float4 e0 = *(const float4*)(wexp + (size_t)n * NH);
    const float4 e1 = *(const float4*)(wexp + (size_t)n * NH + 4);
    const float4 e2 = *(const float4*)(wexp + (size_t)n * NH + 8);
    const float4 e3 = *(const float4*)(wexp + (size_t)n * NH + 12);
#define ACC1(h, e) { acc[h][0] = fmaf(e, l0, acc[h][0]); acc[h][1] = fmaf(e, l1, acc[h][1]); \
                     acc[h][2] = fmaf(e, l2, acc[h][2]); acc[h][3] = fmaf(e, l3, acc[h][3]); }
    ACC1(0, e0.x)  ACC1(1, e0.y)  ACC1(2, e0.z)  ACC1(3, e0.w)
    ACC1(4, e1.x)  ACC1(5, e1.y)  ACC1(6, e1.z)  ACC1(7, e1.w)
    ACC1(8, e2.x)  ACC1(9, e2.y)  ACC1(10, e2.z) ACC1(11, e2.w)
    ACC1(12, e3.x) ACC1(13, e3.y) ACC1(14, e3.z) ACC1(15, e3.w)
#undef ACC1
  }
  #pragma unroll
  for (int hh = 0; hh < NH; hh++){
    float4 o; o.x = acc[hh][0]; o.y = acc[hh][1]; o.z = acc[hh][2]; o.w = acc[hh][3];
    *(float4*)(upart + ((size_t)bb * NH + hh) * DM + t * 4) = o;
  }
}

// ---------- two-level reduce of upart ----------
__global__ void k_ured1(const float* __restrict__ upart, float* __restrict__ up2){
  const int idx = (blockIdx.x & 63) * 256 + threadIdx.x;   // 0..16383
  const int sl  = blockIdx.x >> 6;                          // 0..15
  float s = 0.f;
  for (int b = sl * 16; b < sl * 16 + 16; b++) s += upart[(size_t)b * (NH * DM) + idx];
  up2[(size_t)sl * (NH * DM) + idx] = s;
}

__global__ void k_ured2(const float* __restrict__ up2, const float* __restrict__ ms,
                        float* __restrict__ u){
  const int idx = blockIdx.x * 256 + threadIdx.x;   // 0..16383
  const int hh = idx >> 10;
  float s = 0.f;
  #pragma unroll
  for (int sl = 0; sl < 16; sl++) s += up2[(size_t)sl * (NH * DM) + idx];
  u[idx] = s / ms[16 + hh];
}

// ---------- out_center[o] = u[head(o),:] . Wv[o,:] ----------
__global__ void k_oc(const float* __restrict__ u, const float* __restrict__ Wv,
                     float* __restrict__ oc){
  int lane = threadIdx.x & 63, wid = threadIdx.x >> 6;
  #pragma unroll
  for (int oi = 0; oi < 4; oi++){
    int o = blockIdx.x * 16 + wid * 4 + oi;
    const float* ur = u + (size_t)(o >> 6) * DM;
    const float* wr = Wv + (size_t)o * DM;
    float a = 0.f;
    #pragma unroll
    for (int j = 0; j < 16; j++) a = fmaf(ur[lane + 64 * j], wr[lane + 64 * j], a);
    a = wred(a);
    if (lane == 0) oc[o] = a;
  }
}

// ---------- hcnew[o] = h[c,o] + 0.5 * oc . Wo[o,:] ----------
__global__ void k_delta(const float* __restrict__ oc, const float* __restrict__ Wo,
                        const float* __restrict__ h, const int* __restrict__ cidx,
                        float* __restrict__ hcnew){
  int lane = threadIdx.x & 63, wid = threadIdx.x >> 6;
  int c = *cidx;
  float ov[16];
  #pragma unroll
  for (int j = 0; j < 16; j++) ov[j] = oc[lane + 64 * j];
  #pragma unroll
  for (int oi = 0; oi < 4; oi++){
    int o = blockIdx.x * 16 + wid * 4 + oi;
    const float* wr = Wo + (size_t)o * DM;
    float a = 0.f;
    #pragma unroll
    for (int j = 0; j < 16; j++) a = fmaf(ov[j], wr[lane + 64 * j], a);
    a = wred(a);
    if (lane == 0) hcnew[o] = h[(size_t)c * DM + o] + 0.5f * a;
  }
}

// ---------- rank-1 column biases: gbtot/fbtot ----------
__global__ void k_gbfb(const float* __restrict__ hcnew, const float* __restrict__ gateW,
                       const float* __restrict__ gateB, const float* __restrict__ fuseW1,
                       const float* __restrict__ fuseB1, float* __restrict__ gbtot,
                       float* __restrict__ fbtot){
  int lane = threadIdx.x & 63, wid = threadIdx.x >> 6;
  float hv[16];
  #pragma unroll
  for (int j = 0; j < 16; j++) hv[j] = hcnew[lane + 64 * j];
  #pragma unroll
  for (int oi = 0; oi < 4; oi++){
    int o = blockIdx.x * 16 + wid * 4 + oi;
    const float* gr = gateW + (size_t)o * 2048 + 1024;
    const float* fr = fuseW1 + (size_t)o * 2048 + 1024;
    float ga = 0.f, fa = 0.f;
    #pragma unroll
    for (int j = 0; j < 16; j++){
      ga = fmaf(hv[j], gr[lane + 64 * j], ga);
      fa = fmaf(hv[j], fr[lane + 64 * j], fa);
    }
    ga = wred(ga); fa = wred(fa);
    if (lane == 0){ gbtot[o] = ga + gateB[o]; fbtot[o] = fa + fuseB1[o]; }
  }
}

// ---------- MFMA GEMM, 256x256 tile, BK=64, 8-phase counted-vmcnt, asm ds_read ----------
// FROZEN at the round-10 best (452 us MODE0): rolled K-loop (#pragma unroll 1),
// opaque asm ds_read (no compiler hazard drains), lgkmcnt(0)+sched_barrier per phase,
// counted vmcnt(4) at P4/P8 only, raw s_barrier, 2-way-free XOR swizzle, XCD remap.
#define BM 256
#define BK 64
#define H128 ((size_t)128 * DM)
#define GLL16(gp, lp) __builtin_amdgcn_global_load_lds((const __attribute__((address_space(1))) void*)(gp), (__attribute__((address_space(3))) void*)(lp), 16, 0, 0)
#define SBAR() do { __builtin_amdgcn_sched_barrier(0); \
                    asm volatile("s_barrier" ::: "memory"); \
                    __builtin_amdgcn_sched_barrier(0); } while (0)

#define PHASE(BUF, Q, STG, STL, STK, DOVM) do {                                        \
    if ((Q) == 0){                                                                     \
      _Pragma("unroll")                                                                \
      for (int nj = 0; nj < 4; nj++){                                                  \
        bq[nj][0] = ldsr128(lB + (BUF)*16384 + bBase + nj*1024 + kOff0);               \
        bq[nj][1] = ldsr128(lB + (BUF)*16384 + bBase + nj*1024 + kOff1);               \
      }                                                                                \
    }                                                                                  \
    bf16x8 a00 = ldsr128(lA + (BUF)*16384 + aBase + (2*(Q))*1024   + kOff0);           \
    bf16x8 a01 = ldsr128(lA + (BUF)*16384 + aBase + (2*(Q))*1024   + kOff1);           \
    bf16x8 a10 = ldsr128(lA + (BUF)*16384 + aBase + (2*(Q)+1)*1024 + kOff0);           \
    bf16x8 a11 = ldsr128(lA + (BUF)*16384 + aBase + (2*(Q)+1)*1024 + kOff1);           \
    stage(STG, STL, STK);                                                              \
    SBAR();                                                                            \
    asm volatile("s_waitcnt lgkmcnt(0)" ::: "memory");                                 \
    __builtin_amdgcn_sched_barrier(0);                                                 \
    __builtin_amdgcn_s_setprio(1);                                                     \
    _Pragma("unroll")                                                                  \
    for (int nj = 0; nj < 4; nj++){                                                    \
      acc[2*(Q)][nj]   = MFMA16(a00, bq[nj][0], acc[2*(Q)][nj]);                       \
      acc[2*(Q)][nj]   = MFMA16(a01, bq[nj][1], acc[2*(Q)][nj]);                       \
      acc[2*(Q)+1][nj] = MFMA16(a10, bq[nj][0], acc[2*(Q)+1][nj]);                     \
      acc[2*(Q)+1][nj] = MFMA16(a11, bq[nj][1], acc[2*(Q)+1][nj]);                     \
    }                                                                                  \
    __builtin_amdgcn_s_setprio(0);                                                     \
    if (DOVM){ asm volatile("s_waitcnt vmcnt(4)" ::: "memory"); }                      \
    SBAR();                                                                            \
  } while (0)

template<int MODE>
__launch_bounds__(512, 2)
__global__ void k_gemm(const unsigned short* __restrict__ A, const unsigned short* __restrict__ B,
                       const float* __restrict__ bias0, const float* __restrict__ bias1,
                       const unsigned short* __restrict__ hsrcb, const unsigned short* __restrict__ gate,
                       unsigned short* __restrict__ og, unsigned short* __restrict__ ot,
                       float* __restrict__ of){
  __shared__ __attribute__((aligned(16))) unsigned short lA[32768];
  __shared__ __attribute__((aligned(16))) unsigned short lB[32768];
  const int NWG = (MODE == 0) ? 2048 : 1024;
  const int NYT = (MODE == 0) ? 8 : 4;
  const int bid = blockIdx.x;
  const int remap = (bid & 7) * (NWG >> 3) + (bid >> 3);
  const int m0 = (remap / NYT) * BM, n0 = (remap % NYT) * BM;

  const int tid = threadIdx.x, lane = tid & 63, w = tid >> 6;
  const int wm = w >> 2, wn = w & 3;

  f32x4 acc[8][4];
  #pragma unroll
  for (int i = 0; i < 8; i++){
    #pragma unroll
    for (int j = 0; j < 4; j++){ acc[i][j][0] = 0.f; acc[i][j][1] = 0.f; acc[i][j][2] = 0.f; acc[i][j][3] = 0.f; }
  }

  const int ln3 = lane >> 3;
  const size_t stRow0 = (size_t)(w * 16 + ln3);
  const int sxor = ((lane & 7) ^ ln3) * 8;
  const size_t srcOff0 = stRow0 * DM + sxor;
  const size_t srcOff1 = (stRow0 + 8) * DM + sxor;
  const int dst0 = w * 1024 + lane * 8;
  const int dst1 = dst0 + 512;

  const unsigned short* gA = A + (size_t)m0 * DM;
  const unsigned short* gB = B + (size_t)n0 * DM;

  auto stage = [&](const unsigned short* g, unsigned short* ldsr, int kt){
    GLL16(g + srcOff0 + kt * 64, ldsr + dst0);
    GLL16(g + srcOff1 + kt * 64, ldsr + dst1);
  };

  const int fr = lane & 15;
  const int kq = lane >> 4;
  const int kOff0 = ((kq)     ^ (lane & 7)) * 8;
  const int kOff1 = ((4 + kq) ^ (lane & 7)) * 8;
  const int aBase = wm * 8192 + fr * 64;
  const int bBase = (wn >> 1) * 8192 + ((wn & 1) * 64 + fr) * 64;

  bf16x8 bq[4][2];

  stage(gA,        lA,                0);
  stage(gA + H128, lA + 8192,         0);
  stage(gB,        lB,                0);
  stage(gB + H128, lB + 8192,         0);
  stage(gB,        lB + 16384,        1);
  stage(gB + H128, lB + 16384 + 8192, 1);
  asm volatile("s_waitcnt vmcnt(4)" ::: "memory");
  SBAR();

  #pragma unroll 1
  for (int i = 0; i < 8; i++){
    const int k0 = 2 * i;
    PHASE(0, 0, gA,        lA + 16384,        k0 + 1,        false);
    PHASE(0, 1, gA + H128, lA + 16384 + 8192, k0 + 1,        false);
    PHASE(0, 2, gB,        lB,                (k0 + 2) & 15, false);
    PHASE(0, 3, gB + H128, lB + 8192,         (k0 + 2) & 15, true);
    PHASE(1, 0, gA,        lA,                (k0 + 2) & 15, false);
    PHASE(1, 1, gA + H128, lA + 8192,         (k0 + 2) & 15, false);
    PHASE(1, 2, gB,        lB + 16384,        (k0 + 3) & 15, false);
    PHASE(1, 3, gB + H128, lB + 16384 + 8192, (k0 + 3) & 15, true);
  }

  const int r0 = kq * 4;
  #pragma unroll
  for (int mi = 0; mi < 8; mi++){
    #pragma unroll
    for (int nj = 0; nj < 4; nj++){
      const int gmb = m0 + wm * 128 + mi * 16 + r0;
      const int gn  = n0 + wn * 64 + nj * 16 + fr;
      #pragma unroll
      for (int r = 0; r < 4; r++){
        const int gm = gmb + r;
        const float x = acc[mi][nj][r];
        if (MODE == 0){
          if (gn < 1024){
            const float v = x + bias0[gn];
            og[(size_t)gm * DM + gn] = f2bf(1.0f / (1.0f + __expf(-v)));
          } else {
            const float v = x + bias1[gn - 1024];
            ot[(size_t)gm * DM + (gn - 1024)] = f2bf(v / (1.0f + __expf(-v)));
          }
        } else {
          const float v = x + bias0[gn];
          const float g = bf2f(gate[(size_t)gm * DM + gn]);
          of[(size_t)gm * DM + gn] = bf2f(hsrcb[(size_t)gm * DM + gn]) + 0.5f * g * v;
        }
      }
    }
  }
}

// ---------- overwrite center row ----------
__global__ void k_fixc(const float* __restrict__ hcnew, const int* __restrict__ cidx,
                       float* __restrict__ out){
  int t = threadIdx.x;
  int c = *cidx;
  out[(size_t)c * DM + t] = hcnew[t];
}

extern "C" void kernel_launch(void* const* d_in, const int* in_sizes, int n_in,
                              void* d_out, int out_size, void* d_ws, size_t ws_size,
                              hipStream_t stream){
  const float* h      = (const float*)d_in[0];
  const float* rbf    = (const float*)d_in[1];
  const float* seqsep = (const float*)d_in[2];
  const float* localb = (const float*)d_in[3];
  const float* ncw    = (const float*)d_in[4];
  const float* ncb    = (const float*)d_in[5];
  const float* naw    = (const float*)d_in[6];
  const float* nab    = (const float*)d_in[7];
  const float* Wq     = (const float*)d_in[8];
  const float* Wk     = (const float*)d_in[9];
  const float* Wv     = (const float*)d_in[10];
  const float* Wo     = (const float*)d_in[11];
  const float* Wbias  = (const float*)d_in[12];
  const float* gateW  = (const float*)d_in[13];
  const float* gateB  = (const float*)d_in[14];
  const float* fuseW1 = (const float*)d_in[15];
  const float* fuseB1 = (const float*)d_in[16];
  const float* fuseW2 = (const float*)d_in[17];
  const float* fuseB2 = (const float*)d_in[18];
  const int*   nbr    = (const int*)d_in[19];
  const int*   cidx   = (const int*)d_in[20];
  float* out = (float*)d_out;

  char* p = (char*)d_ws;
  auto alloc = [&](size_t nb){ char* r = p; p += (nb + 255) & ~(size_t)255; return r; };
  float* extra   = (float*)alloc((size_t)NN * DEX * 4);
  float* logitsT = (float*)alloc((size_t)NN * NH * 4);
  float* wexp    = (float*)alloc((size_t)NN * NH * 4);
  float* biasT   = (float*)alloc((size_t)NN * NH * 4);
  float* meanb   = (float*)alloc((size_t)NN * 4);
  float* rstdb   = (float*)alloc((size_t)NN * 4);
  float* ms      = (float*)alloc(32 * 4);
  float* msp     = (float*)alloc((size_t)256 * NH * 2 * 4);
  float* qkt     = (float*)alloc(NH * DM * 4);
  float* u       = (float*)alloc(NH * DM * 4);
  float* hcln    = (float*)alloc(DM * 4);
  float* qv      = (float*)alloc(DM * 4);
  float* oc      = (float*)alloc(DM * 4);
  float* hcnew   = (float*)alloc(DM * 4);
  float* gbtot   = (float*)alloc(DM * 4);
  float* fbtot   = (float*)alloc(DM * 4);
  float* c12     = (float*)alloc(32 * 4);
  float* up2     = (float*)alloc((size_t)16 * NH * DM * 4);
  float* upart   = (float*)alloc((size_t)UB * NH * DM * 4);
  unsigned short* Wcomb = (unsigned short*)alloc((size_t)2048 * 1024 * 2);
  unsigned short* W2b   = (unsigned short*)alloc((size_t)1024 * 1024 * 2);
  unsigned short* Qa    = (unsigned short*)alloc((size_t)NH * DM * 2);
  unsigned short* hbf   = (unsigned short*)alloc((size_t)NN * DM * 2);
  unsigned short* gateb = (unsigned short*)alloc((size_t)NN * DM * 2);
  unsigned short* t1    = (unsigned short*)alloc((size_t)NN * DM * 2);
  if ((size_t)(p - (char*)d_ws) > ws_size) return;  // clean fail instead of corruption

  hipMemsetAsync(extra, 0, (size_t)NN * DEX * 4, stream);
  k_scatter<<<(KNB * DEX + 255) / 256, 256, 0, stream>>>(localb, nbr, extra);
  k_convw<<<(3 * 1024 * 1024) / 256, 256, 0, stream>>>(gateW, fuseW1, fuseW2, Wcomb, W2b);
  k_cln<<<1, 256, 0, stream>>>(h, cidx, ncw, ncb, hcln);
  k_q<<<64, 256, 0, stream>>>(hcln, Wq, qv);
  k_qkt<<<64, 256, 0, stream>>>(qv, Wk, qkt);
  k_c12<<<32, 64, 0, stream>>>(qkt, naw, nab, c12);
  k_qa<<<64, 256, 0, stream>>>(qkt, naw, Qa);
  k_bias<<<NN * NH / 256, 256, 0, stream>>>(rbf, seqsep, extra, Wbias, biasT);
  k_lnpass<<<NN / 8, 256, 0, stream>>>(h, meanb, rstdb, hbf);
  k_logits<<<1024, 256, 0, stream>>>(hbf, Qa, meanb, rstdb, c12, biasT, logitsT);
  k_smpart<<<256, 256, 0, stream>>>(logitsT, msp);
  k_smcomb<<<1, 64, 0, stream>>>(msp, ms);
  k_expw<<<NN * NH / 4 / 256, 256, 0, stream>>>(logitsT, ms, wexp);
  k_upart<<<UB, 256, 0, stream>>>(hbf, meanb, rstdb, naw, nab, wexp, upart);
  k_ured1<<<1024, 256, 0, stream>>>(upart, up2);
  k_ured2<<<64, 256, 0, stream>>>(up2, ms, u);
  k_oc<<<64, 256, 0, stream>>>(u, Wv, oc);
  k_delta<<<64, 256, 0, stream>>>(oc, Wo, h, cidx, hcnew);
  k_gbfb<<<64, 256, 0, stream>>>(hcnew, gateW, gateB, fuseW1, fuseB1, gbtot, fbtot);
  k_gemm<0><<<2048, 512, 0, stream>>>(hbf, Wcomb, gbtot, fbtot, nullptr, nullptr, gateb, t1, nullptr);
  k_gemm<1><<<1024, 512, 0, stream>>>(t1, W2b, fuseB2, nullptr, hbf, gateb, nullptr, nullptr, out);
  k_fixc<<<1, 1024, 0, stream>>>(hcnew, cidx, out);
}